// Round 2
// baseline (309.513 us; speedup 1.0000x reference)
//
#include <hip/hip_runtime.h>
#include <hip/hip_bf16.h>

// Fused GATConv + proj + LayerNorm + ReLU. N=50000, E=800000, F_IN=128, H=4, C=16, D=128.
//   k_wprep   : pack W into bf16 hi/lo MFMA B-fragments (fragment order, coalesced reads later)
//   k_xw_mfma : xp = x@W via split-bf16 MFMA (3-term: fp32-grade accuracy), + a_src/a_dst logits
//   k_hist/scan/fill : CSR by destination
//   k_agg     : single-pass segment softmax (no max-sub; exact in exact math) + aggregation
//               + proj (global float4 proj_w) + LN + ReLU.  LDS 9KB -> high occupancy.

#define LEAKY(x) ((x) > 0.f ? (x) : 0.2f * (x))

typedef __attribute__((ext_vector_type(8))) short bf16x8;
typedef __attribute__((ext_vector_type(4))) float f32x4;

static __device__ __forceinline__ unsigned short f2bf_rne(float f) {
    unsigned u = __float_as_uint(f);
    return (unsigned short)((u + 0x7FFFu + ((u >> 16) & 1u)) >> 16);
}
static __device__ __forceinline__ float bf2f(unsigned short h) {
    return __uint_as_float(((unsigned)h) << 16);
}

// Pack W[k][n] (128x64 f32) into bf16 hi/lo fragments, laid out so the GEMM reads
// frag[(t*4+s)*64 + lane] as one 16B bf16x8: element j -> k = s*32 + (lane>>4)*8 + j,
// n = t*16 + (lane&15).
__global__ __launch_bounds__(256) void k_wprep(const float* __restrict__ W,
                                               unsigned short* __restrict__ Whf,
                                               unsigned short* __restrict__ Wlf)
{
    int idx = blockIdx.x * 256 + threadIdx.x;
    if (idx >= 16 * 64 * 8) return;
    int j = idx & 7, lane = (idx >> 3) & 63, ts = idx >> 9;
    int t = ts >> 2, s = ts & 3;
    int k = s * 32 + ((lane >> 4) << 3) + j;
    int n = t * 16 + (lane & 15);
    float w = W[k * 64 + n];
    unsigned short wh = f2bf_rne(w);
    Whf[idx] = wh;
    Wlf[idx] = f2bf_rne(w - bf2f(wh));
}

__global__ __launch_bounds__(256) void k_xw_mfma(
    const float* __restrict__ x,
    const unsigned short* __restrict__ Whf, const unsigned short* __restrict__ Wlf,
    const float* __restrict__ att_src, const float* __restrict__ att_dst,
    float* __restrict__ xp, float* __restrict__ a_src, float* __restrict__ a_dst,
    int n_nodes)
{
    int t = threadIdx.x, w = t >> 6, lane = t & 63;
    int mbase = blockIdx.x * 64 + w * 16;
    int mrow = lane & 15, kg = lane >> 4;
    int node = mbase + mrow;
    if (node >= n_nodes) node = n_nodes - 1;   // clamp; results for fake rows never stored

    // A fragments: lane holds x[node][s*32 + kg*8 + 0..7], split into bf16 hi/lo
    bf16x8 ah[4], al[4];
#pragma unroll
    for (int s = 0; s < 4; s++) {
        const float* px = x + (size_t)node * 128 + s * 32 + kg * 8;
        float4 v0 = *(const float4*)px;
        float4 v1 = *(const float4*)(px + 4);
        float f0 = v0.x, f1 = v0.y, f2 = v0.z, f3 = v0.w;
        float f4 = v1.x, f5 = v1.y, f6 = v1.z, f7 = v1.w;
        unsigned short h0 = f2bf_rne(f0), h1 = f2bf_rne(f1), h2 = f2bf_rne(f2), h3 = f2bf_rne(f3);
        unsigned short h4 = f2bf_rne(f4), h5 = f2bf_rne(f5), h6 = f2bf_rne(f6), h7 = f2bf_rne(f7);
        ah[s][0]=(short)h0; ah[s][1]=(short)h1; ah[s][2]=(short)h2; ah[s][3]=(short)h3;
        ah[s][4]=(short)h4; ah[s][5]=(short)h5; ah[s][6]=(short)h6; ah[s][7]=(short)h7;
        al[s][0]=(short)f2bf_rne(f0-bf2f(h0)); al[s][1]=(short)f2bf_rne(f1-bf2f(h1));
        al[s][2]=(short)f2bf_rne(f2-bf2f(h2)); al[s][3]=(short)f2bf_rne(f3-bf2f(h3));
        al[s][4]=(short)f2bf_rne(f4-bf2f(h4)); al[s][5]=(short)f2bf_rne(f5-bf2f(h5));
        al[s][6]=(short)f2bf_rne(f6-bf2f(h6)); al[s][7]=(short)f2bf_rne(f7-bf2f(h7));
    }

    f32x4 acc[4];
#pragma unroll
    for (int tt = 0; tt < 4; tt++) acc[tt] = (f32x4){0.f, 0.f, 0.f, 0.f};

#pragma unroll
    for (int tt = 0; tt < 4; tt++) {
#pragma unroll
        for (int s = 0; s < 4; s++) {
            size_t fi = (size_t)(((tt * 4 + s) * 64 + lane) * 8);
            bf16x8 bh = *(const bf16x8*)(Whf + fi);
            bf16x8 bl = *(const bf16x8*)(Wlf + fi);
            acc[tt] = __builtin_amdgcn_mfma_f32_16x16x32_bf16(ah[s], bh, acc[tt], 0, 0, 0);
            acc[tt] = __builtin_amdgcn_mfma_f32_16x16x32_bf16(ah[s], bl, acc[tt], 0, 0, 0);
            acc[tt] = __builtin_amdgcn_mfma_f32_16x16x32_bf16(al[s], bh, acc[tt], 0, 0, 0);
        }
    }

    // Epilogue: D layout col=lane&15, row=(lane>>4)*4+reg. Tile tt == head tt.
#pragma unroll
    for (int tt = 0; tt < 4; tt++) {
        float asv = att_src[tt * 16 + mrow];
        float adv = att_dst[tt * 16 + mrow];
#pragma unroll
        for (int r = 0; r < 4; r++) {
            float v = acc[tt][r];
            int n2 = mbase + kg * 4 + r;
            bool ok = (n2 < n_nodes);
            if (ok) xp[(size_t)n2 * 64 + tt * 16 + mrow] = v;
            float ts = v * asv;
            float td = v * adv;
#pragma unroll
            for (int off = 8; off; off >>= 1) {
                ts += __shfl_xor(ts, off);
                td += __shfl_xor(td, off);
            }
            if (mrow == 0 && ok) {
                a_src[n2 * 4 + tt] = ts;
                a_dst[n2 * 4 + tt] = td;
            }
        }
    }
}

__global__ __launch_bounds__(256) void k_hist(const int* __restrict__ dst, int* __restrict__ deg, int E)
{
    int e = blockIdx.x * 256 + threadIdx.x;
    if (e < E) atomicAdd(&deg[dst[e]], 1);
}

__global__ __launch_bounds__(256) void k_scan1(const int* __restrict__ deg, int* __restrict__ row_ptr,
                                               int* __restrict__ partial, int n)
{
    __shared__ int sh[256];
    int t = threadIdx.x, g = blockIdx.x * 256 + t;
    int v = (g < n) ? deg[g] : 0;
    sh[t] = v; __syncthreads();
    for (int off = 1; off < 256; off <<= 1) {
        int u = (t >= off) ? sh[t - off] : 0;
        __syncthreads();
        sh[t] += u;
        __syncthreads();
    }
    if (g < n) row_ptr[g] = sh[t];
    if (t == 255) partial[blockIdx.x] = sh[255];
}

__global__ __launch_bounds__(256) void k_scan2(int* __restrict__ partial, int nblk)
{
    __shared__ int sh[256];
    int t = threadIdx.x;
    int v = (t < nblk) ? partial[t] : 0;
    sh[t] = v; __syncthreads();
    for (int off = 1; off < 256; off <<= 1) {
        int u = (t >= off) ? sh[t - off] : 0;
        __syncthreads();
        sh[t] += u;
        __syncthreads();
    }
    if (t < nblk) partial[t] = sh[t] - v;
}

__global__ __launch_bounds__(256) void k_scan3(const int* __restrict__ deg, int* __restrict__ row_ptr,
                                               int* __restrict__ cursor, const int* __restrict__ partial,
                                               int n, int E_total)
{
    int g = blockIdx.x * 256 + threadIdx.x;
    if (g < n) {
        int rp = partial[blockIdx.x] + row_ptr[g] - deg[g];
        row_ptr[g] = rp;
        cursor[g] = rp;
    }
    if (g == 0) row_ptr[n] = E_total;
}

__global__ __launch_bounds__(256) void k_fill(const int* __restrict__ src, const int* __restrict__ dst,
                                              int* __restrict__ cursor, int* __restrict__ colsrc, int E)
{
    int e = blockIdx.x * 256 + threadIdx.x;
    if (e < E) {
        int d = dst[e];
        int p = atomicAdd(&cursor[d], 1);
        colsrc[p] = src[e];
    }
}

__global__ __launch_bounds__(256) void k_agg(
    const float* __restrict__ xp, const float* __restrict__ a_src, const float* __restrict__ a_dst,
    const int* __restrict__ row_ptr, const int* __restrict__ colsrc,
    const float* __restrict__ bias, const float* __restrict__ proj_w, const float* __restrict__ proj_b,
    const float* __restrict__ gamma, const float* __restrict__ beta,
    float* __restrict__ out, int n_nodes)
{
    __shared__ float rowbuf[16][64];      // aggregated rows (+bias): 4 KB
    __shared__ float alpha_s[4][64][4];   // per-wave edge alphas (4 heads): 4 KB
    __shared__ int   sstage[4][64];       // per-wave staged src indices: 1 KB
    int t = threadIdx.x, w = t >> 6, lane = t & 63, h = lane >> 4;
    int nbase = blockIdx.x * 16 + w * 4;
    float bi = bias[lane];

    for (int i = 0; i < 4; i++) {
        int n = nbase + i;
        if (n >= n_nodes) continue;
        int rp0 = row_ptr[n], rp1 = row_ptr[n + 1];
        float4 ad4 = *(const float4*)&a_dst[(size_t)n * 4];
        float acc = 0.f, den = 0.f;
        for (int base = rp0; base < rp1; base += 64) {
            int cnt = rp1 - base; if (cnt > 64) cnt = 64;
            // lane-parallel: one edge per lane, all 4 heads' unnormalized alphas
            if (lane < cnt) {
                int s = colsrc[base + lane];
                float4 as4 = *(const float4*)&a_src[(size_t)s * 4];
                float4 p;
                p.x = __expf(LEAKY(as4.x + ad4.x));
                p.y = __expf(LEAKY(as4.y + ad4.y));
                p.z = __expf(LEAKY(as4.z + ad4.z));
                p.w = __expf(LEAKY(as4.w + ad4.w));
                sstage[w][lane] = s;
                *(float4*)&alpha_s[w][lane][0] = p;
            } else {
                sstage[w][lane] = 0;
                *(float4*)&alpha_s[w][lane][0] = make_float4(0.f, 0.f, 0.f, 0.f);
            }
            // same-wave LDS write->read: in-order per wave, no barrier needed
            int cnt8 = (cnt + 7) & ~7;
            for (int j = 0; j < cnt8; j += 8) {
                float a0, a1, a2, a3, a4, a5, a6, a7;
                int   s0, s1, s2, s3, s4, s5, s6, s7;
                s0 = sstage[w][j+0]; a0 = alpha_s[w][j+0][h];
                s1 = sstage[w][j+1]; a1 = alpha_s[w][j+1][h];
                s2 = sstage[w][j+2]; a2 = alpha_s[w][j+2][h];
                s3 = sstage[w][j+3]; a3 = alpha_s[w][j+3][h];
                s4 = sstage[w][j+4]; a4 = alpha_s[w][j+4][h];
                s5 = sstage[w][j+5]; a5 = alpha_s[w][j+5][h];
                s6 = sstage[w][j+6]; a6 = alpha_s[w][j+6][h];
                s7 = sstage[w][j+7]; a7 = alpha_s[w][j+7][h];
                float v0 = xp[(size_t)s0 * 64 + lane];
                float v1 = xp[(size_t)s1 * 64 + lane];
                float v2 = xp[(size_t)s2 * 64 + lane];
                float v3 = xp[(size_t)s3 * 64 + lane];
                float v4 = xp[(size_t)s4 * 64 + lane];
                float v5 = xp[(size_t)s5 * 64 + lane];
                float v6 = xp[(size_t)s6 * 64 + lane];
                float v7 = xp[(size_t)s7 * 64 + lane];
                den += a0 + a1 + a2 + a3 + a4 + a5 + a6 + a7;
                acc += a0*v0 + a1*v1 + a2*v2 + a3*v3 + a4*v4 + a5*v5 + a6*v6 + a7*v7;
            }
        }
        rowbuf[w * 4 + i][lane] = acc / (den + 1e-16f) + bi;
    }

    // projection: y[n][d] = sum_j proj_w[d][j] * row[n][j] + proj_b[d]; d = lane, lane+64
    float y00 = proj_b[lane], y01 = proj_b[lane + 64];
    float y10 = y00, y11 = y01, y20 = y00, y21 = y01, y30 = y00, y31 = y01;
    const float* pwr0 = proj_w + (size_t)lane * 64;
    const float* pwr1 = proj_w + (size_t)(lane + 64) * 64;
    int w4 = w * 4;
#pragma unroll
    for (int j = 0; j < 64; j += 4) {
        float4 p0 = *(const float4*)(pwr0 + j);
        float4 p1 = *(const float4*)(pwr1 + j);
        float4 r0 = *(const float4*)&rowbuf[w4 + 0][j];
        float4 r1 = *(const float4*)&rowbuf[w4 + 1][j];
        float4 r2 = *(const float4*)&rowbuf[w4 + 2][j];
        float4 r3 = *(const float4*)&rowbuf[w4 + 3][j];
        y00 += r0.x*p0.x + r0.y*p0.y + r0.z*p0.z + r0.w*p0.w;
        y01 += r0.x*p1.x + r0.y*p1.y + r0.z*p1.z + r0.w*p1.w;
        y10 += r1.x*p0.x + r1.y*p0.y + r1.z*p0.z + r1.w*p0.w;
        y11 += r1.x*p1.x + r1.y*p1.y + r1.z*p1.z + r1.w*p1.w;
        y20 += r2.x*p0.x + r2.y*p0.y + r2.z*p0.z + r2.w*p0.w;
        y21 += r2.x*p1.x + r2.y*p1.y + r2.z*p1.z + r2.w*p1.w;
        y30 += r3.x*p0.x + r3.y*p0.y + r3.z*p0.z + r3.w*p0.w;
        y31 += r3.x*p1.x + r3.y*p1.y + r3.z*p1.z + r3.w*p1.w;
    }

    float g0 = gamma[lane], g1 = gamma[lane + 64];
    float b0 = beta[lane],  b1 = beta[lane + 64];
    float yv0[4] = {y00, y10, y20, y30};
    float yv1[4] = {y01, y11, y21, y31};
#pragma unroll
    for (int i = 0; i < 4; i++) {
        int n = nbase + i;
        if (n >= n_nodes) continue;
        float v0 = yv0[i], v1 = yv1[i];
        float S = v0 + v1, Q = v0 * v0 + v1 * v1;
#pragma unroll
        for (int off = 32; off; off >>= 1) {
            S += __shfl_xor(S, off);
            Q += __shfl_xor(Q, off);
        }
        float mu  = S * (1.f / 128.f);
        float var = Q * (1.f / 128.f) - mu * mu;
        float inv = rsqrtf(var + 1e-5f);
        float o0 = fmaxf((v0 - mu) * inv * g0 + b0, 0.f);
        float o1 = fmaxf((v1 - mu) * inv * g1 + b1, 0.f);
        out[(size_t)n * 128 + lane]      = o0;
        out[(size_t)n * 128 + lane + 64] = o1;
    }
}

extern "C" void kernel_launch(void* const* d_in, const int* in_sizes, int n_in,
                              void* d_out, int out_size, void* d_ws, size_t ws_size,
                              hipStream_t stream)
{
    const float* x       = (const float*)d_in[0];
    const int*   ei      = (const int*)  d_in[1];
    const float* W       = (const float*)d_in[2];
    const float* att_src = (const float*)d_in[3];
    const float* att_dst = (const float*)d_in[4];
    const float* bias    = (const float*)d_in[5];
    const float* proj_w  = (const float*)d_in[6];
    const float* proj_b  = (const float*)d_in[7];
    const float* gamma   = (const float*)d_in[8];
    const float* beta    = (const float*)d_in[9];

    int N = in_sizes[0] / 128;
    int E = in_sizes[1] / 2;
    const int* srcIdx = ei;
    const int* dstIdx = ei + E;

    char* ws = (char*)d_ws;
    float* xp      = (float*)ws; ws += (size_t)N * 64 * 4;
    float* a_src   = (float*)ws; ws += (size_t)N * 4 * 4;
    float* a_dst   = (float*)ws; ws += (size_t)N * 4 * 4;
    int*   deg     = (int*)ws;   ws += (size_t)N * 4;
    int*   row_ptr = (int*)ws;   ws += (size_t)(N + 1) * 4;
    int*   cursor  = (int*)ws;   ws += (size_t)N * 4;
    int*   partial = (int*)ws;   ws += 256 * 4;
    int*   colsrc  = (int*)ws;   ws += (size_t)E * 4;
    unsigned short* Whf = (unsigned short*)ws; ws += 16 * 64 * 8 * 2;
    unsigned short* Wlf = (unsigned short*)ws; ws += 16 * 64 * 8 * 2;

    int nb16 = (N + 15) / 16;
    int nb64 = (N + 63) / 64;
    int nbE  = (E + 255) / 256;
    int nblk = (N + 255) / 256;

    hipMemsetAsync(deg, 0, (size_t)N * 4, stream);
    k_wprep<<<(16 * 64 * 8 + 255) / 256, 256, 0, stream>>>(W, Whf, Wlf);
    k_xw_mfma<<<nb64, 256, 0, stream>>>(x, Whf, Wlf, att_src, att_dst, xp, a_src, a_dst, N);
    k_hist<<<nbE,  256, 0, stream>>>(dstIdx, deg, E);
    k_scan1<<<nblk, 256, 0, stream>>>(deg, row_ptr, partial, N);
    k_scan2<<<1,    256, 0, stream>>>(partial, nblk);
    k_scan3<<<nblk, 256, 0, stream>>>(deg, row_ptr, cursor, partial, N, E);
    k_fill<<<nbE,  256, 0, stream>>>(srcIdx, dstIdx, cursor, colsrc, E);
    k_agg <<<nb16, 256, 0, stream>>>(xp, a_src, a_dst, row_ptr, colsrc,
                                     bias, proj_w, proj_b, gamma, beta,
                                     (float*)d_out, N);
}

// Round 3
// 169.993 us; speedup vs baseline: 1.8207x; 1.8207x over previous
//
#include <hip/hip_runtime.h>
#include <hip/hip_bf16.h>

// Fused GATConv + proj + LayerNorm + ReLU. N=50000, E=800000, F_IN=128, H=4, C=16, D=128.
//   k_prep    : pack W and proj_w into bf16 hi/lo MFMA B-fragments; fold bias into proj_b
//   k_xw_mfma : xp = x@W via split-bf16 MFMA + a_src/a_dst logits
//   k_hist/scan/fill : CSR by destination
//   k_agg2    : single-pass segment softmax + aggregation (gather kernel, VGPR<=64 for occupancy)
//   k_proj    : (aggr) @ proj_w^T + pb2, LayerNorm, ReLU via split-bf16 MFMA

#define LEAKY(x) ((x) > 0.f ? (x) : 0.2f * (x))

typedef __attribute__((ext_vector_type(8))) short bf16x8;
typedef __attribute__((ext_vector_type(4))) float f32x4;

static __device__ __forceinline__ unsigned short f2bf_rne(float f) {
    unsigned u = __float_as_uint(f);
    return (unsigned short)((u + 0x7FFFu + ((u >> 16) & 1u)) >> 16);
}
static __device__ __forceinline__ float bf2f(unsigned short h) {
    return __uint_as_float(((unsigned)h) << 16);
}

// One prep kernel:
//  idx [0, 8192)        : W fragments  (16 tiles-of-(t,s): t=0..3 n-tile, s=0..3 k-chunk)
//  idx [8192, 16384)    : proj_w fragments (8 d-tiles x 2 k-chunks)
//  idx [16384, 16512)   : pb2[d] = proj_b[d] + sum_j bias[j]*proj_w[d][j]
__global__ __launch_bounds__(256) void k_prep(
    const float* __restrict__ W, const float* __restrict__ bias,
    const float* __restrict__ proj_w, const float* __restrict__ proj_b,
    unsigned short* __restrict__ Whf, unsigned short* __restrict__ Wlf,
    unsigned short* __restrict__ Phf, unsigned short* __restrict__ Plf,
    float* __restrict__ pb2)
{
    int idx = blockIdx.x * 256 + threadIdx.x;
    if (idx < 8192) {
        int j = idx & 7, lane = (idx >> 3) & 63, ts = idx >> 9;
        int t = ts >> 2, s = ts & 3;
        int k = s * 32 + ((lane >> 4) << 3) + j;
        int n = t * 16 + (lane & 15);
        float w = W[k * 64 + n];
        unsigned short wh = f2bf_rne(w);
        Whf[idx] = wh;
        Wlf[idx] = f2bf_rne(w - bf2f(wh));
    } else if (idx < 16384) {
        int i2 = idx - 8192;
        int j = i2 & 7, lane = (i2 >> 3) & 63, ts = i2 >> 9;
        int t = ts >> 1, s = ts & 1;
        int k = s * 32 + ((lane >> 4) << 3) + j;   // 0..63
        int d = t * 16 + (lane & 15);              // 0..127
        float w = proj_w[d * 64 + k];
        unsigned short wh = f2bf_rne(w);
        Phf[i2] = wh;
        Plf[i2] = f2bf_rne(w - bf2f(wh));
    } else if (idx < 16384 + 128) {
        int d = idx - 16384;
        float s = proj_b[d];
        for (int j = 0; j < 64; j++) s += bias[j] * proj_w[d * 64 + j];
        pb2[d] = s;
    }
}

__global__ __launch_bounds__(256) void k_xw_mfma(
    const float* __restrict__ x,
    const unsigned short* __restrict__ Whf, const unsigned short* __restrict__ Wlf,
    const float* __restrict__ att_src, const float* __restrict__ att_dst,
    float* __restrict__ xp, float* __restrict__ a_src, float* __restrict__ a_dst,
    int n_nodes)
{
    int t = threadIdx.x, w = t >> 6, lane = t & 63;
    int mbase = blockIdx.x * 64 + w * 16;
    int mrow = lane & 15, kg = lane >> 4;
    int node = mbase + mrow;
    if (node >= n_nodes) node = n_nodes - 1;   // clamp; fake rows never stored

    bf16x8 ah[4], al[4];
#pragma unroll
    for (int s = 0; s < 4; s++) {
        const float* px = x + (size_t)node * 128 + s * 32 + kg * 8;
        float4 v0 = *(const float4*)px;
        float4 v1 = *(const float4*)(px + 4);
        float f[8] = {v0.x, v0.y, v0.z, v0.w, v1.x, v1.y, v1.z, v1.w};
#pragma unroll
        for (int j = 0; j < 8; j++) {
            unsigned short h = f2bf_rne(f[j]);
            ah[s][j] = (short)h;
            al[s][j] = (short)f2bf_rne(f[j] - bf2f(h));
        }
    }

    f32x4 acc[4];
#pragma unroll
    for (int tt = 0; tt < 4; tt++) acc[tt] = (f32x4){0.f, 0.f, 0.f, 0.f};

#pragma unroll
    for (int tt = 0; tt < 4; tt++) {
#pragma unroll
        for (int s = 0; s < 4; s++) {
            size_t fi = (size_t)(((tt * 4 + s) * 64 + lane) * 8);
            bf16x8 bh = *(const bf16x8*)(Whf + fi);
            bf16x8 bl = *(const bf16x8*)(Wlf + fi);
            acc[tt] = __builtin_amdgcn_mfma_f32_16x16x32_bf16(ah[s], bh, acc[tt], 0, 0, 0);
            acc[tt] = __builtin_amdgcn_mfma_f32_16x16x32_bf16(ah[s], bl, acc[tt], 0, 0, 0);
            acc[tt] = __builtin_amdgcn_mfma_f32_16x16x32_bf16(al[s], bh, acc[tt], 0, 0, 0);
        }
    }

    // D layout: col=lane&15, row=(lane>>4)*4+reg. Tile tt == head tt.
#pragma unroll
    for (int tt = 0; tt < 4; tt++) {
        float asv = att_src[tt * 16 + mrow];
        float adv = att_dst[tt * 16 + mrow];
#pragma unroll
        for (int r = 0; r < 4; r++) {
            float v = acc[tt][r];
            int n2 = mbase + kg * 4 + r;
            bool ok = (n2 < n_nodes);
            if (ok) xp[(size_t)n2 * 64 + tt * 16 + mrow] = v;
            float ts = v * asv;
            float td = v * adv;
#pragma unroll
            for (int off = 8; off; off >>= 1) {
                ts += __shfl_xor(ts, off);
                td += __shfl_xor(td, off);
            }
            if (mrow == 0 && ok) {
                a_src[n2 * 4 + tt] = ts;
                a_dst[n2 * 4 + tt] = td;
            }
        }
    }
}

__global__ __launch_bounds__(256) void k_hist(const int* __restrict__ dst, int* __restrict__ deg, int E)
{
    int e = blockIdx.x * 256 + threadIdx.x;
    if (e < E) atomicAdd(&deg[dst[e]], 1);
}

__global__ __launch_bounds__(256) void k_scan1(const int* __restrict__ deg, int* __restrict__ row_ptr,
                                               int* __restrict__ partial, int n)
{
    __shared__ int sh[256];
    int t = threadIdx.x, g = blockIdx.x * 256 + t;
    int v = (g < n) ? deg[g] : 0;
    sh[t] = v; __syncthreads();
    for (int off = 1; off < 256; off <<= 1) {
        int u = (t >= off) ? sh[t - off] : 0;
        __syncthreads();
        sh[t] += u;
        __syncthreads();
    }
    if (g < n) row_ptr[g] = sh[t];
    if (t == 255) partial[blockIdx.x] = sh[255];
}

__global__ __launch_bounds__(256) void k_scan2(int* __restrict__ partial, int nblk)
{
    __shared__ int sh[256];
    int t = threadIdx.x;
    int v = (t < nblk) ? partial[t] : 0;
    sh[t] = v; __syncthreads();
    for (int off = 1; off < 256; off <<= 1) {
        int u = (t >= off) ? sh[t - off] : 0;
        __syncthreads();
        sh[t] += u;
        __syncthreads();
    }
    if (t < nblk) partial[t] = sh[t] - v;
}

__global__ __launch_bounds__(256) void k_scan3(const int* __restrict__ deg, int* __restrict__ row_ptr,
                                               int* __restrict__ cursor, const int* __restrict__ partial,
                                               int n, int E_total)
{
    int g = blockIdx.x * 256 + threadIdx.x;
    if (g < n) {
        int rp = partial[blockIdx.x] + row_ptr[g] - deg[g];
        row_ptr[g] = rp;
        cursor[g] = rp;
    }
    if (g == 0) row_ptr[n] = E_total;
}

__global__ __launch_bounds__(256) void k_fill(const int* __restrict__ src, const int* __restrict__ dst,
                                              int* __restrict__ cursor, int* __restrict__ colsrc, int E)
{
    int e = blockIdx.x * 256 + threadIdx.x;
    if (e < E) {
        int d = dst[e];
        int p = atomicAdd(&cursor[d], 1);
        colsrc[p] = src[e];
    }
}

// Gather kernel: one node per wave. VGPR kept <=64 (launch_bounds min-waves=8)
// so 8 waves/SIMD hide the L3 gather latency of xp[src].
__global__ __launch_bounds__(256, 8) void k_agg2(
    const float* __restrict__ xp, const float* __restrict__ a_src, const float* __restrict__ a_dst,
    const int* __restrict__ row_ptr, const int* __restrict__ colsrc,
    float* __restrict__ aggr, int n_nodes)
{
    __shared__ int   sstage[4][64];       // 1 KB
    __shared__ float alpha_s[4][64][4];   // 4 KB
    int t = threadIdx.x, w = t >> 6, lane = t & 63, h = lane >> 4;
    int n = blockIdx.x * 4 + w;
    if (n >= n_nodes) return;
    int rp0 = row_ptr[n], rp1 = row_ptr[n + 1];
    float4 ad4 = *(const float4*)&a_dst[(size_t)n * 4];
    float acc = 0.f, den = 0.f;
    for (int base = rp0; base < rp1; base += 64) {
        int cnt = rp1 - base; if (cnt > 64) cnt = 64;
        int s = 0;
        float4 p = make_float4(0.f, 0.f, 0.f, 0.f);
        if (lane < cnt) {
            s = colsrc[base + lane];
            float4 as4 = *(const float4*)&a_src[(size_t)s * 4];
            p.x = __expf(LEAKY(as4.x + ad4.x));
            p.y = __expf(LEAKY(as4.y + ad4.y));
            p.z = __expf(LEAKY(as4.z + ad4.z));
            p.w = __expf(LEAKY(as4.w + ad4.w));
        }
        sstage[w][lane] = s;
        *(float4*)&alpha_s[w][lane][0] = p;
        // same-wave LDS write->read is in-order; no barrier needed
        int cnt4 = (cnt + 3) & ~3;
        for (int j = 0; j < cnt4; j += 4) {
            int s0 = sstage[w][j+0], s1 = sstage[w][j+1];
            int s2 = sstage[w][j+2], s3 = sstage[w][j+3];
            float a0 = alpha_s[w][j+0][h], a1 = alpha_s[w][j+1][h];
            float a2 = alpha_s[w][j+2][h], a3 = alpha_s[w][j+3][h];
            float v0 = xp[(size_t)((unsigned)s0 * 64u + lane)];
            float v1 = xp[(size_t)((unsigned)s1 * 64u + lane)];
            float v2 = xp[(size_t)((unsigned)s2 * 64u + lane)];
            float v3 = xp[(size_t)((unsigned)s3 * 64u + lane)];
            den += a0 + a1 + a2 + a3;
            acc += a0 * v0 + a1 * v1 + a2 * v2 + a3 * v3;
        }
    }
    aggr[(size_t)n * 64 + lane] = acc / (den + 1e-16f);
}

// proj + LN + ReLU via split-bf16 MFMA: out = LN(aggr @ proj_w^T + pb2)*gamma+beta, relu
__global__ __launch_bounds__(256, 4) void k_proj(
    const float* __restrict__ aggr,
    const unsigned short* __restrict__ Phf, const unsigned short* __restrict__ Plf,
    const float* __restrict__ pb2, const float* __restrict__ gamma, const float* __restrict__ beta,
    float* __restrict__ out, int n_nodes)
{
    __shared__ float pb_s[128], g_s[128], b_s[128];
    int t = threadIdx.x;
    if (t < 128) { pb_s[t] = pb2[t]; g_s[t] = gamma[t]; b_s[t] = beta[t]; }
    __syncthreads();
    int w = t >> 6, lane = t & 63;
    int mbase = blockIdx.x * 64 + w * 16;
    int mrow = lane & 15, kg = lane >> 4;
    int node = mbase + mrow;
    if (node >= n_nodes) node = n_nodes - 1;

    bf16x8 ah[2], al[2];
#pragma unroll
    for (int s = 0; s < 2; s++) {
        const float* pa = aggr + (size_t)node * 64 + s * 32 + kg * 8;
        float4 v0 = *(const float4*)pa;
        float4 v1 = *(const float4*)(pa + 4);
        float f[8] = {v0.x, v0.y, v0.z, v0.w, v1.x, v1.y, v1.z, v1.w};
#pragma unroll
        for (int j = 0; j < 8; j++) {
            unsigned short hh = f2bf_rne(f[j]);
            ah[s][j] = (short)hh;
            al[s][j] = (short)f2bf_rne(f[j] - bf2f(hh));
        }
    }

    f32x4 acc[8];
#pragma unroll
    for (int tt = 0; tt < 8; tt++) acc[tt] = (f32x4){0.f, 0.f, 0.f, 0.f};
#pragma unroll
    for (int tt = 0; tt < 8; tt++) {
#pragma unroll
        for (int s = 0; s < 2; s++) {
            size_t fi = (size_t)(((tt * 2 + s) * 64 + lane) * 8);
            bf16x8 bh = *(const bf16x8*)(Phf + fi);
            bf16x8 bl = *(const bf16x8*)(Plf + fi);
            acc[tt] = __builtin_amdgcn_mfma_f32_16x16x32_bf16(ah[s], bh, acc[tt], 0, 0, 0);
            acc[tt] = __builtin_amdgcn_mfma_f32_16x16x32_bf16(ah[s], bl, acc[tt], 0, 0, 0);
            acc[tt] = __builtin_amdgcn_mfma_f32_16x16x32_bf16(al[s], bh, acc[tt], 0, 0, 0);
        }
    }

    // D layout: d = tt*16 + (lane&15), node_row = kg*4 + r
#pragma unroll
    for (int r = 0; r < 4; r++) {
        int nr = mbase + kg * 4 + r;
        float vv[8];
        float S = 0.f, Q = 0.f;
#pragma unroll
        for (int tt = 0; tt < 8; tt++) {
            float v = acc[tt][r] + pb_s[tt * 16 + mrow];
            vv[tt] = v;
            S += v;
            Q += v * v;
        }
#pragma unroll
        for (int off = 8; off; off >>= 1) {
            S += __shfl_xor(S, off);
            Q += __shfl_xor(Q, off);
        }
        float mu  = S * (1.f / 128.f);
        float var = Q * (1.f / 128.f) - mu * mu;
        float inv = rsqrtf(var + 1e-5f);
        if (nr < n_nodes) {
#pragma unroll
            for (int tt = 0; tt < 8; tt++) {
                int d = tt * 16 + mrow;
                float o = fmaxf((vv[tt] - mu) * inv * g_s[d] + b_s[d], 0.f);
                out[(size_t)nr * 128 + d] = o;
            }
        }
    }
}

extern "C" void kernel_launch(void* const* d_in, const int* in_sizes, int n_in,
                              void* d_out, int out_size, void* d_ws, size_t ws_size,
                              hipStream_t stream)
{
    const float* x       = (const float*)d_in[0];
    const int*   ei      = (const int*)  d_in[1];
    const float* W       = (const float*)d_in[2];
    const float* att_src = (const float*)d_in[3];
    const float* att_dst = (const float*)d_in[4];
    const float* bias    = (const float*)d_in[5];
    const float* proj_w  = (const float*)d_in[6];
    const float* proj_b  = (const float*)d_in[7];
    const float* gamma   = (const float*)d_in[8];
    const float* beta    = (const float*)d_in[9];

    int N = in_sizes[0] / 128;
    int E = in_sizes[1] / 2;
    const int* srcIdx = ei;
    const int* dstIdx = ei + E;

    char* ws = (char*)d_ws;
    float* xp      = (float*)ws; ws += (size_t)N * 64 * 4;
    float* aggr    = (float*)ws; ws += (size_t)N * 64 * 4;
    float* a_src   = (float*)ws; ws += (size_t)N * 4 * 4;
    float* a_dst   = (float*)ws; ws += (size_t)N * 4 * 4;
    int*   deg     = (int*)ws;   ws += (size_t)N * 4;
    int*   row_ptr = (int*)ws;   ws += (size_t)(N + 1) * 4;
    int*   cursor  = (int*)ws;   ws += (size_t)N * 4;
    int*   partial = (int*)ws;   ws += 256 * 4;
    int*   colsrc  = (int*)ws;   ws += (size_t)E * 4;
    unsigned short* Whf = (unsigned short*)ws; ws += 8192 * 2;
    unsigned short* Wlf = (unsigned short*)ws; ws += 8192 * 2;
    unsigned short* Phf = (unsigned short*)ws; ws += 8192 * 2;
    unsigned short* Plf = (unsigned short*)ws; ws += 8192 * 2;
    float* pb2 = (float*)ws; ws += 128 * 4;

    int nb64 = (N + 63) / 64;
    int nbE  = (E + 255) / 256;
    int nblk = (N + 255) / 256;

    hipMemsetAsync(deg, 0, (size_t)N * 4, stream);
    k_prep<<<(16512 + 255) / 256, 256, 0, stream>>>(W, bias, proj_w, proj_b, Whf, Wlf, Phf, Plf, pb2);
    k_xw_mfma<<<nb64, 256, 0, stream>>>(x, Whf, Wlf, att_src, att_dst, xp, a_src, a_dst, N);
    k_hist<<<nbE,  256, 0, stream>>>(dstIdx, deg, E);
    k_scan1<<<nblk, 256, 0, stream>>>(deg, row_ptr, partial, N);
    k_scan2<<<1,    256, 0, stream>>>(partial, nblk);
    k_scan3<<<nblk, 256, 0, stream>>>(deg, row_ptr, cursor, partial, N, E);
    k_fill<<<nbE,  256, 0, stream>>>(srcIdx, dstIdx, cursor, colsrc, E);
    k_agg2<<<(N + 3) / 4, 256, 0, stream>>>(xp, a_src, a_dst, row_ptr, colsrc, aggr, N);
    k_proj<<<nb64, 256, 0, stream>>>(aggr, Phf, Plf, pb2, gamma, beta, (float*)d_out, N);
}

// Round 4
// 130.155 us; speedup vs baseline: 2.3780x; 1.3061x over previous
//
#include <hip/hip_runtime.h>
#include <hip/hip_bf16.h>

// Fused GATConv + proj + LayerNorm + ReLU. N=50000, E=800000, F_IN=128, H=4, C=16, D=128.
//   k_prep    : pack W and proj_w into bf16 hi/lo MFMA B-fragments; fold bias into proj_b
//   k_xw_mfma : xp = x@W via split-bf16 MFMA + a_src/a_dst logits
//   k_rank    : deg[dst]++ per edge, capturing per-edge rank (ONE atomic pass total)
//   k_scan*   : exclusive prefix sum -> row_ptr (CSR by destination)
//   k_fill    : atomic-free scatter: colsrc[row_ptr[dst]+rank] = src
//   k_agg2    : single-pass segment softmax + aggregation (gather kernel, high occupancy)
//   k_proj    : (aggr) @ proj_w^T + pb2, LayerNorm, ReLU via split-bf16 MFMA

#define LEAKY(x) ((x) > 0.f ? (x) : 0.2f * (x))

typedef __attribute__((ext_vector_type(8))) short bf16x8;
typedef __attribute__((ext_vector_type(4))) float f32x4;

static __device__ __forceinline__ unsigned short f2bf_rne(float f) {
    unsigned u = __float_as_uint(f);
    return (unsigned short)((u + 0x7FFFu + ((u >> 16) & 1u)) >> 16);
}
static __device__ __forceinline__ float bf2f(unsigned short h) {
    return __uint_as_float(((unsigned)h) << 16);
}

__global__ __launch_bounds__(256) void k_prep(
    const float* __restrict__ W, const float* __restrict__ bias,
    const float* __restrict__ proj_w, const float* __restrict__ proj_b,
    unsigned short* __restrict__ Whf, unsigned short* __restrict__ Wlf,
    unsigned short* __restrict__ Phf, unsigned short* __restrict__ Plf,
    float* __restrict__ pb2)
{
    int idx = blockIdx.x * 256 + threadIdx.x;
    if (idx < 8192) {
        int j = idx & 7, lane = (idx >> 3) & 63, ts = idx >> 9;
        int t = ts >> 2, s = ts & 3;
        int k = s * 32 + ((lane >> 4) << 3) + j;
        int n = t * 16 + (lane & 15);
        float w = W[k * 64 + n];
        unsigned short wh = f2bf_rne(w);
        Whf[idx] = wh;
        Wlf[idx] = f2bf_rne(w - bf2f(wh));
    } else if (idx < 16384) {
        int i2 = idx - 8192;
        int j = i2 & 7, lane = (i2 >> 3) & 63, ts = i2 >> 9;
        int t = ts >> 1, s = ts & 1;
        int k = s * 32 + ((lane >> 4) << 3) + j;   // 0..63
        int d = t * 16 + (lane & 15);              // 0..127
        float w = proj_w[d * 64 + k];
        unsigned short wh = f2bf_rne(w);
        Phf[i2] = wh;
        Plf[i2] = f2bf_rne(w - bf2f(wh));
    } else if (idx < 16384 + 128) {
        int d = idx - 16384;
        float s = proj_b[d];
        for (int j = 0; j < 64; j++) s += bias[j] * proj_w[d * 64 + j];
        pb2[d] = s;
    }
}

__global__ __launch_bounds__(256) void k_xw_mfma(
    const float* __restrict__ x,
    const unsigned short* __restrict__ Whf, const unsigned short* __restrict__ Wlf,
    const float* __restrict__ att_src, const float* __restrict__ att_dst,
    float* __restrict__ xp, float* __restrict__ a_src, float* __restrict__ a_dst,
    int n_nodes)
{
    int t = threadIdx.x, w = t >> 6, lane = t & 63;
    int mbase = blockIdx.x * 64 + w * 16;
    int mrow = lane & 15, kg = lane >> 4;
    int node = mbase + mrow;
    if (node >= n_nodes) node = n_nodes - 1;   // clamp; fake rows never stored

    bf16x8 ah[4], al[4];
#pragma unroll
    for (int s = 0; s < 4; s++) {
        const float* px = x + (size_t)node * 128 + s * 32 + kg * 8;
        float4 v0 = *(const float4*)px;
        float4 v1 = *(const float4*)(px + 4);
        float f[8] = {v0.x, v0.y, v0.z, v0.w, v1.x, v1.y, v1.z, v1.w};
#pragma unroll
        for (int j = 0; j < 8; j++) {
            unsigned short h = f2bf_rne(f[j]);
            ah[s][j] = (short)h;
            al[s][j] = (short)f2bf_rne(f[j] - bf2f(h));
        }
    }

    f32x4 acc[4];
#pragma unroll
    for (int tt = 0; tt < 4; tt++) acc[tt] = (f32x4){0.f, 0.f, 0.f, 0.f};

#pragma unroll
    for (int tt = 0; tt < 4; tt++) {
#pragma unroll
        for (int s = 0; s < 4; s++) {
            size_t fi = (size_t)(((tt * 4 + s) * 64 + lane) * 8);
            bf16x8 bh = *(const bf16x8*)(Whf + fi);
            bf16x8 bl = *(const bf16x8*)(Wlf + fi);
            acc[tt] = __builtin_amdgcn_mfma_f32_16x16x32_bf16(ah[s], bh, acc[tt], 0, 0, 0);
            acc[tt] = __builtin_amdgcn_mfma_f32_16x16x32_bf16(ah[s], bl, acc[tt], 0, 0, 0);
            acc[tt] = __builtin_amdgcn_mfma_f32_16x16x32_bf16(al[s], bh, acc[tt], 0, 0, 0);
        }
    }

    // D layout: col=lane&15, row=(lane>>4)*4+reg. Tile tt == head tt.
#pragma unroll
    for (int tt = 0; tt < 4; tt++) {
        float asv = att_src[tt * 16 + mrow];
        float adv = att_dst[tt * 16 + mrow];
#pragma unroll
        for (int r = 0; r < 4; r++) {
            float v = acc[tt][r];
            int n2 = mbase + kg * 4 + r;
            bool ok = (n2 < n_nodes);
            if (ok) xp[(size_t)n2 * 64 + tt * 16 + mrow] = v;
            float ts = v * asv;
            float td = v * adv;
#pragma unroll
            for (int off = 8; off; off >>= 1) {
                ts += __shfl_xor(ts, off);
                td += __shfl_xor(td, off);
            }
            if (mrow == 0 && ok) {
                a_src[n2 * 4 + tt] = ts;
                a_dst[n2 * 4 + tt] = td;
            }
        }
    }
}

// ONE atomic pass: histogram + per-edge rank capture.
__global__ __launch_bounds__(256) void k_rank(const int* __restrict__ dst, int* __restrict__ deg,
                                              int* __restrict__ erank, int E)
{
    int e = blockIdx.x * 256 + threadIdx.x;
    if (e < E) erank[e] = atomicAdd(&deg[dst[e]], 1);
}

__global__ __launch_bounds__(256) void k_scan1(const int* __restrict__ deg, int* __restrict__ row_ptr,
                                               int* __restrict__ partial, int n)
{
    __shared__ int sh[256];
    int t = threadIdx.x, g = blockIdx.x * 256 + t;
    int v = (g < n) ? deg[g] : 0;
    sh[t] = v; __syncthreads();
    for (int off = 1; off < 256; off <<= 1) {
        int u = (t >= off) ? sh[t - off] : 0;
        __syncthreads();
        sh[t] += u;
        __syncthreads();
    }
    if (g < n) row_ptr[g] = sh[t];
    if (t == 255) partial[blockIdx.x] = sh[255];
}

__global__ __launch_bounds__(256) void k_scan2(int* __restrict__ partial, int nblk)
{
    __shared__ int sh[256];
    int t = threadIdx.x;
    int v = (t < nblk) ? partial[t] : 0;
    sh[t] = v; __syncthreads();
    for (int off = 1; off < 256; off <<= 1) {
        int u = (t >= off) ? sh[t - off] : 0;
        __syncthreads();
        sh[t] += u;
        __syncthreads();
    }
    if (t < nblk) partial[t] = sh[t] - v;
}

__global__ __launch_bounds__(256) void k_scan3(const int* __restrict__ deg, int* __restrict__ row_ptr,
                                               const int* __restrict__ partial, int n, int E_total)
{
    int g = blockIdx.x * 256 + threadIdx.x;
    if (g < n) {
        row_ptr[g] = partial[blockIdx.x] + row_ptr[g] - deg[g];   // exclusive global
    }
    if (g == 0) row_ptr[n] = E_total;
}

// Atomic-free CSR fill: slot = row_ptr[dst] + rank.
__global__ __launch_bounds__(256) void k_fill(const int* __restrict__ src, const int* __restrict__ dst,
                                              const int* __restrict__ erank, const int* __restrict__ row_ptr,
                                              int* __restrict__ colsrc, int E)
{
    int e = blockIdx.x * 256 + threadIdx.x;
    if (e < E) {
        colsrc[row_ptr[dst[e]] + erank[e]] = src[e];
    }
}

// Gather kernel: one node per wave. VGPR kept low for occupancy to hide gather latency.
__global__ __launch_bounds__(256, 8) void k_agg2(
    const float* __restrict__ xp, const float* __restrict__ a_src, const float* __restrict__ a_dst,
    const int* __restrict__ row_ptr, const int* __restrict__ colsrc,
    float* __restrict__ aggr, int n_nodes)
{
    __shared__ int   sstage[4][64];       // 1 KB
    __shared__ float alpha_s[4][64][4];   // 4 KB
    int t = threadIdx.x, w = t >> 6, lane = t & 63, h = lane >> 4;
    int n = blockIdx.x * 4 + w;
    if (n >= n_nodes) return;
    int rp0 = row_ptr[n], rp1 = row_ptr[n + 1];
    float4 ad4 = *(const float4*)&a_dst[(size_t)n * 4];
    float acc = 0.f, den = 0.f;
    for (int base = rp0; base < rp1; base += 64) {
        int cnt = rp1 - base; if (cnt > 64) cnt = 64;
        int s = 0;
        float4 p = make_float4(0.f, 0.f, 0.f, 0.f);
        if (lane < cnt) {
            s = colsrc[base + lane];
            float4 as4 = *(const float4*)&a_src[(size_t)s * 4];
            p.x = __expf(LEAKY(as4.x + ad4.x));
            p.y = __expf(LEAKY(as4.y + ad4.y));
            p.z = __expf(LEAKY(as4.z + ad4.z));
            p.w = __expf(LEAKY(as4.w + ad4.w));
        }
        sstage[w][lane] = s;
        *(float4*)&alpha_s[w][lane][0] = p;
        // same-wave LDS write->read is in-order; no barrier needed
        int cnt4 = (cnt + 3) & ~3;
        for (int j = 0; j < cnt4; j += 4) {
            int s0 = sstage[w][j+0], s1 = sstage[w][j+1];
            int s2 = sstage[w][j+2], s3 = sstage[w][j+3];
            float a0 = alpha_s[w][j+0][h], a1 = alpha_s[w][j+1][h];
            float a2 = alpha_s[w][j+2][h], a3 = alpha_s[w][j+3][h];
            float v0 = xp[(size_t)((unsigned)s0 * 64u + lane)];
            float v1 = xp[(size_t)((unsigned)s1 * 64u + lane)];
            float v2 = xp[(size_t)((unsigned)s2 * 64u + lane)];
            float v3 = xp[(size_t)((unsigned)s3 * 64u + lane)];
            den += a0 + a1 + a2 + a3;
            acc += a0 * v0 + a1 * v1 + a2 * v2 + a3 * v3;
        }
    }
    aggr[(size_t)n * 64 + lane] = acc / (den + 1e-16f);
}

// proj + LN + ReLU via split-bf16 MFMA
__global__ __launch_bounds__(256, 4) void k_proj(
    const float* __restrict__ aggr,
    const unsigned short* __restrict__ Phf, const unsigned short* __restrict__ Plf,
    const float* __restrict__ pb2, const float* __restrict__ gamma, const float* __restrict__ beta,
    float* __restrict__ out, int n_nodes)
{
    __shared__ float pb_s[128], g_s[128], b_s[128];
    int t = threadIdx.x;
    if (t < 128) { pb_s[t] = pb2[t]; g_s[t] = gamma[t]; b_s[t] = beta[t]; }
    __syncthreads();
    int w = t >> 6, lane = t & 63;
    int mbase = blockIdx.x * 64 + w * 16;
    int mrow = lane & 15, kg = lane >> 4;
    int node = mbase + mrow;
    if (node >= n_nodes) node = n_nodes - 1;

    bf16x8 ah[2], al[2];
#pragma unroll
    for (int s = 0; s < 2; s++) {
        const float* pa = aggr + (size_t)node * 64 + s * 32 + kg * 8;
        float4 v0 = *(const float4*)pa;
        float4 v1 = *(const float4*)(pa + 4);
        float f[8] = {v0.x, v0.y, v0.z, v0.w, v1.x, v1.y, v1.z, v1.w};
#pragma unroll
        for (int j = 0; j < 8; j++) {
            unsigned short hh = f2bf_rne(f[j]);
            ah[s][j] = (short)hh;
            al[s][j] = (short)f2bf_rne(f[j] - bf2f(hh));
        }
    }

    f32x4 acc[8];
#pragma unroll
    for (int tt = 0; tt < 8; tt++) acc[tt] = (f32x4){0.f, 0.f, 0.f, 0.f};
#pragma unroll
    for (int tt = 0; tt < 8; tt++) {
#pragma unroll
        for (int s = 0; s < 2; s++) {
            size_t fi = (size_t)(((tt * 2 + s) * 64 + lane) * 8);
            bf16x8 bh = *(const bf16x8*)(Phf + fi);
            bf16x8 bl = *(const bf16x8*)(Plf + fi);
            acc[tt] = __builtin_amdgcn_mfma_f32_16x16x32_bf16(ah[s], bh, acc[tt], 0, 0, 0);
            acc[tt] = __builtin_amdgcn_mfma_f32_16x16x32_bf16(ah[s], bl, acc[tt], 0, 0, 0);
            acc[tt] = __builtin_amdgcn_mfma_f32_16x16x32_bf16(al[s], bh, acc[tt], 0, 0, 0);
        }
    }

    // D layout: d = tt*16 + (lane&15), node_row = kg*4 + r
#pragma unroll
    for (int r = 0; r < 4; r++) {
        int nr = mbase + kg * 4 + r;
        float vv[8];
        float S = 0.f, Q = 0.f;
#pragma unroll
        for (int tt = 0; tt < 8; tt++) {
            float v = acc[tt][r] + pb_s[tt * 16 + mrow];
            vv[tt] = v;
            S += v;
            Q += v * v;
        }
#pragma unroll
        for (int off = 8; off; off >>= 1) {
            S += __shfl_xor(S, off);
            Q += __shfl_xor(Q, off);
        }
        float mu  = S * (1.f / 128.f);
        float var = Q * (1.f / 128.f) - mu * mu;
        float inv = rsqrtf(var + 1e-5f);
        if (nr < n_nodes) {
#pragma unroll
            for (int tt = 0; tt < 8; tt++) {
                int d = tt * 16 + mrow;
                float o = fmaxf((vv[tt] - mu) * inv * g_s[d] + b_s[d], 0.f);
                out[(size_t)nr * 128 + d] = o;
            }
        }
    }
}

extern "C" void kernel_launch(void* const* d_in, const int* in_sizes, int n_in,
                              void* d_out, int out_size, void* d_ws, size_t ws_size,
                              hipStream_t stream)
{
    const float* x       = (const float*)d_in[0];
    const int*   ei      = (const int*)  d_in[1];
    const float* W       = (const float*)d_in[2];
    const float* att_src = (const float*)d_in[3];
    const float* att_dst = (const float*)d_in[4];
    const float* bias    = (const float*)d_in[5];
    const float* proj_w  = (const float*)d_in[6];
    const float* proj_b  = (const float*)d_in[7];
    const float* gamma   = (const float*)d_in[8];
    const float* beta    = (const float*)d_in[9];

    int N = in_sizes[0] / 128;
    int E = in_sizes[1] / 2;
    const int* srcIdx = ei;
    const int* dstIdx = ei + E;

    char* ws = (char*)d_ws;
    float* xp      = (float*)ws; ws += (size_t)N * 64 * 4;
    float* aggr    = (float*)ws; ws += (size_t)N * 64 * 4;
    float* a_src   = (float*)ws; ws += (size_t)N * 4 * 4;
    float* a_dst   = (float*)ws; ws += (size_t)N * 4 * 4;
    int*   deg     = (int*)ws;   ws += (size_t)N * 4;
    int*   row_ptr = (int*)ws;   ws += (size_t)(N + 1) * 4;
    int*   partial = (int*)ws;   ws += 256 * 4;
    int*   colsrc  = (int*)ws;   ws += (size_t)E * 4;
    int*   erank   = (int*)ws;   ws += (size_t)E * 4;
    unsigned short* Whf = (unsigned short*)ws; ws += 8192 * 2;
    unsigned short* Wlf = (unsigned short*)ws; ws += 8192 * 2;
    unsigned short* Phf = (unsigned short*)ws; ws += 8192 * 2;
    unsigned short* Plf = (unsigned short*)ws; ws += 8192 * 2;
    float* pb2 = (float*)ws; ws += 128 * 4;

    int nb64 = (N + 63) / 64;
    int nbE  = (E + 255) / 256;
    int nblk = (N + 255) / 256;

    hipMemsetAsync(deg, 0, (size_t)N * 4, stream);
    k_prep<<<(16512 + 255) / 256, 256, 0, stream>>>(W, bias, proj_w, proj_b, Whf, Wlf, Phf, Plf, pb2);
    k_xw_mfma<<<nb64, 256, 0, stream>>>(x, Whf, Wlf, att_src, att_dst, xp, a_src, a_dst, N);
    k_rank<<<nbE,  256, 0, stream>>>(dstIdx, deg, erank, E);
    k_scan1<<<nblk, 256, 0, stream>>>(deg, row_ptr, partial, N);
    k_scan2<<<1,    256, 0, stream>>>(partial, nblk);
    k_scan3<<<nblk, 256, 0, stream>>>(deg, row_ptr, partial, N, E);
    k_fill<<<nbE,  256, 0, stream>>>(srcIdx, dstIdx, erank, row_ptr, colsrc, E);
    k_agg2<<<(N + 3) / 4, 256, 0, stream>>>(xp, a_src, a_dst, row_ptr, colsrc, aggr, N);
    k_proj<<<nb64, 256, 0, stream>>>(aggr, Phf, Plf, pb2, gamma, beta, (float*)d_out, N);
}

// Round 5
// 121.476 us; speedup vs baseline: 2.5479x; 1.0715x over previous
//
#include <hip/hip_runtime.h>
#include <hip/hip_bf16.h>

// Fused GATConv + proj + LayerNorm + ReLU. N=50000, E=800000, F_IN=128, H=4, C=16, D=128.
//   k_prep    : zero deg + pack W and proj_w into bf16 hi/lo MFMA B-fragments; fold bias
//   k_xw_mfma : xp = x@W via split-bf16 MFMA (xp stored bf16) + a_src/a_dst logits (f32)
//   k_rank    : deg[dst]++ per edge, capturing per-edge rank (ONE atomic pass total)
//   k_scan*   : exclusive prefix sum -> row_ptr (CSR by destination)
//   k_fill    : atomic-free scatter: colsrc[row_ptr[dst]+rank] = src
//   k_agg2    : single-pass segment softmax + aggregation (bf16 gather, high occupancy)
//   k_proj    : (aggr) @ proj_w^T + pb2, LayerNorm, ReLU via split-bf16 MFMA

#define LEAKY(x) ((x) > 0.f ? (x) : 0.2f * (x))

typedef __attribute__((ext_vector_type(8))) short bf16x8;
typedef __attribute__((ext_vector_type(4))) float f32x4;

static __device__ __forceinline__ unsigned short f2bf_rne(float f) {
    unsigned u = __float_as_uint(f);
    return (unsigned short)((u + 0x7FFFu + ((u >> 16) & 1u)) >> 16);
}
static __device__ __forceinline__ float bf2f(unsigned short h) {
    return __uint_as_float(((unsigned)h) << 16);
}

// idx [0,8192): W frags; [8192,16384): proj_w frags; [16384,16512): pb2; [16512,16512+N): deg=0
__global__ __launch_bounds__(256) void k_prep(
    const float* __restrict__ W, const float* __restrict__ bias,
    const float* __restrict__ proj_w, const float* __restrict__ proj_b,
    unsigned short* __restrict__ Whf, unsigned short* __restrict__ Wlf,
    unsigned short* __restrict__ Phf, unsigned short* __restrict__ Plf,
    float* __restrict__ pb2, int* __restrict__ deg, int n_nodes)
{
    int idx = blockIdx.x * 256 + threadIdx.x;
    if (idx < 8192) {
        int j = idx & 7, lane = (idx >> 3) & 63, ts = idx >> 9;
        int t = ts >> 2, s = ts & 3;
        int k = s * 32 + ((lane >> 4) << 3) + j;
        int n = t * 16 + (lane & 15);
        float w = W[k * 64 + n];
        unsigned short wh = f2bf_rne(w);
        Whf[idx] = wh;
        Wlf[idx] = f2bf_rne(w - bf2f(wh));
    } else if (idx < 16384) {
        int i2 = idx - 8192;
        int j = i2 & 7, lane = (i2 >> 3) & 63, ts = i2 >> 9;
        int t = ts >> 1, s = ts & 1;
        int k = s * 32 + ((lane >> 4) << 3) + j;   // 0..63
        int d = t * 16 + (lane & 15);              // 0..127
        float w = proj_w[d * 64 + k];
        unsigned short wh = f2bf_rne(w);
        Phf[i2] = wh;
        Plf[i2] = f2bf_rne(w - bf2f(wh));
    } else if (idx < 16384 + 128) {
        int d = idx - 16384;
        float s = proj_b[d];
        for (int j = 0; j < 64; j++) s += bias[j] * proj_w[d * 64 + j];
        pb2[d] = s;
    } else if (idx >= 16512 && idx < 16512 + n_nodes) {
        deg[idx - 16512] = 0;
    }
}

__global__ __launch_bounds__(256) void k_xw_mfma(
    const float* __restrict__ x,
    const unsigned short* __restrict__ Whf, const unsigned short* __restrict__ Wlf,
    const float* __restrict__ att_src, const float* __restrict__ att_dst,
    unsigned short* __restrict__ xp, float* __restrict__ a_src, float* __restrict__ a_dst,
    int n_nodes)
{
    int t = threadIdx.x, w = t >> 6, lane = t & 63;
    int mbase = blockIdx.x * 64 + w * 16;
    int mrow = lane & 15, kg = lane >> 4;
    int node = mbase + mrow;
    if (node >= n_nodes) node = n_nodes - 1;   // clamp; fake rows never stored

    bf16x8 ah[4], al[4];
#pragma unroll
    for (int s = 0; s < 4; s++) {
        const float* px = x + (size_t)node * 128 + s * 32 + kg * 8;
        float4 v0 = *(const float4*)px;
        float4 v1 = *(const float4*)(px + 4);
        float f[8] = {v0.x, v0.y, v0.z, v0.w, v1.x, v1.y, v1.z, v1.w};
#pragma unroll
        for (int j = 0; j < 8; j++) {
            unsigned short h = f2bf_rne(f[j]);
            ah[s][j] = (short)h;
            al[s][j] = (short)f2bf_rne(f[j] - bf2f(h));
        }
    }

    f32x4 acc[4];
#pragma unroll
    for (int tt = 0; tt < 4; tt++) acc[tt] = (f32x4){0.f, 0.f, 0.f, 0.f};

#pragma unroll
    for (int tt = 0; tt < 4; tt++) {
#pragma unroll
        for (int s = 0; s < 4; s++) {
            size_t fi = (size_t)(((tt * 4 + s) * 64 + lane) * 8);
            bf16x8 bh = *(const bf16x8*)(Whf + fi);
            bf16x8 bl = *(const bf16x8*)(Wlf + fi);
            acc[tt] = __builtin_amdgcn_mfma_f32_16x16x32_bf16(ah[s], bh, acc[tt], 0, 0, 0);
            acc[tt] = __builtin_amdgcn_mfma_f32_16x16x32_bf16(ah[s], bl, acc[tt], 0, 0, 0);
            acc[tt] = __builtin_amdgcn_mfma_f32_16x16x32_bf16(al[s], bh, acc[tt], 0, 0, 0);
        }
    }

    // D layout: col=lane&15, row=(lane>>4)*4+reg. Tile tt == head tt.
#pragma unroll
    for (int tt = 0; tt < 4; tt++) {
        float asv = att_src[tt * 16 + mrow];
        float adv = att_dst[tt * 16 + mrow];
#pragma unroll
        for (int r = 0; r < 4; r++) {
            float v = acc[tt][r];
            int n2 = mbase + kg * 4 + r;
            bool ok = (n2 < n_nodes);
            if (ok) xp[(size_t)n2 * 64 + tt * 16 + mrow] = f2bf_rne(v);
            float ts = v * asv;
            float td = v * adv;
#pragma unroll
            for (int off = 8; off; off >>= 1) {
                ts += __shfl_xor(ts, off);
                td += __shfl_xor(td, off);
            }
            if (mrow == 0 && ok) {
                a_src[n2 * 4 + tt] = ts;
                a_dst[n2 * 4 + tt] = td;
            }
        }
    }
}

// ONE atomic pass: histogram + per-edge rank capture.
__global__ __launch_bounds__(256) void k_rank(const int* __restrict__ dst, int* __restrict__ deg,
                                              int* __restrict__ erank, int E)
{
    int e = blockIdx.x * 256 + threadIdx.x;
    if (e < E) erank[e] = atomicAdd(&deg[dst[e]], 1);
}

__global__ __launch_bounds__(256) void k_scan1(const int* __restrict__ deg, int* __restrict__ row_ptr,
                                               int* __restrict__ partial, int n)
{
    __shared__ int sh[256];
    int t = threadIdx.x, g = blockIdx.x * 256 + t;
    int v = (g < n) ? deg[g] : 0;
    sh[t] = v; __syncthreads();
    for (int off = 1; off < 256; off <<= 1) {
        int u = (t >= off) ? sh[t - off] : 0;
        __syncthreads();
        sh[t] += u;
        __syncthreads();
    }
    if (g < n) row_ptr[g] = sh[t];
    if (t == 255) partial[blockIdx.x] = sh[255];
}

__global__ __launch_bounds__(256) void k_scan2(int* __restrict__ partial, int nblk)
{
    __shared__ int sh[256];
    int t = threadIdx.x;
    int v = (t < nblk) ? partial[t] : 0;
    sh[t] = v; __syncthreads();
    for (int off = 1; off < 256; off <<= 1) {
        int u = (t >= off) ? sh[t - off] : 0;
        __syncthreads();
        sh[t] += u;
        __syncthreads();
    }
    if (t < nblk) partial[t] = sh[t] - v;
}

__global__ __launch_bounds__(256) void k_scan3(const int* __restrict__ deg, int* __restrict__ row_ptr,
                                               const int* __restrict__ partial, int n, int E_total)
{
    int g = blockIdx.x * 256 + threadIdx.x;
    if (g < n) {
        row_ptr[g] = partial[blockIdx.x] + row_ptr[g] - deg[g];   // exclusive global
    }
    if (g == 0) row_ptr[n] = E_total;
}

// Atomic-free CSR fill: slot = row_ptr[dst] + rank.
__global__ __launch_bounds__(256) void k_fill(const int* __restrict__ src, const int* __restrict__ dst,
                                              const int* __restrict__ erank, const int* __restrict__ row_ptr,
                                              int* __restrict__ colsrc, int E)
{
    int e = blockIdx.x * 256 + threadIdx.x;
    if (e < E) {
        colsrc[row_ptr[dst[e]] + erank[e]] = src[e];
    }
}

// Gather kernel: one node per wave. bf16 xp halves gather bytes; VGPR low for occupancy.
__global__ __launch_bounds__(256, 8) void k_agg2(
    const unsigned short* __restrict__ xp, const float* __restrict__ a_src, const float* __restrict__ a_dst,
    const int* __restrict__ row_ptr, const int* __restrict__ colsrc,
    float* __restrict__ aggr, int n_nodes)
{
    __shared__ int   sstage[4][64];       // 1 KB
    __shared__ float alpha_s[4][64][4];   // 4 KB
    int t = threadIdx.x, w = t >> 6, lane = t & 63, h = lane >> 4;
    int n = blockIdx.x * 4 + w;
    if (n >= n_nodes) return;
    int rp0 = row_ptr[n], rp1 = row_ptr[n + 1];
    float4 ad4 = *(const float4*)&a_dst[(size_t)n * 4];
    float acc = 0.f, den = 0.f;
    for (int base = rp0; base < rp1; base += 64) {
        int cnt = rp1 - base; if (cnt > 64) cnt = 64;
        int s = 0;
        float4 p = make_float4(0.f, 0.f, 0.f, 0.f);
        if (lane < cnt) {
            s = colsrc[base + lane];
            float4 as4 = *(const float4*)&a_src[(size_t)s * 4];
            p.x = __expf(LEAKY(as4.x + ad4.x));
            p.y = __expf(LEAKY(as4.y + ad4.y));
            p.z = __expf(LEAKY(as4.z + ad4.z));
            p.w = __expf(LEAKY(as4.w + ad4.w));
        }
        sstage[w][lane] = s;
        *(float4*)&alpha_s[w][lane][0] = p;
        // same-wave LDS write->read is in-order; no barrier needed
        int cnt4 = (cnt + 3) & ~3;
        for (int j = 0; j < cnt4; j += 4) {
            int s0 = sstage[w][j+0], s1 = sstage[w][j+1];
            int s2 = sstage[w][j+2], s3 = sstage[w][j+3];
            float a0 = alpha_s[w][j+0][h], a1 = alpha_s[w][j+1][h];
            float a2 = alpha_s[w][j+2][h], a3 = alpha_s[w][j+3][h];
            float v0 = bf2f(xp[(size_t)((unsigned)s0 * 64u + lane)]);
            float v1 = bf2f(xp[(size_t)((unsigned)s1 * 64u + lane)]);
            float v2 = bf2f(xp[(size_t)((unsigned)s2 * 64u + lane)]);
            float v3 = bf2f(xp[(size_t)((unsigned)s3 * 64u + lane)]);
            den += a0 + a1 + a2 + a3;
            acc += a0 * v0 + a1 * v1 + a2 * v2 + a3 * v3;
        }
    }
    aggr[(size_t)n * 64 + lane] = acc / (den + 1e-16f);
}

// proj + LN + ReLU via split-bf16 MFMA
__global__ __launch_bounds__(256, 4) void k_proj(
    const float* __restrict__ aggr,
    const unsigned short* __restrict__ Phf, const unsigned short* __restrict__ Plf,
    const float* __restrict__ pb2, const float* __restrict__ gamma, const float* __restrict__ beta,
    float* __restrict__ out, int n_nodes)
{
    __shared__ float pb_s[128], g_s[128], b_s[128];
    int t = threadIdx.x;
    if (t < 128) { pb_s[t] = pb2[t]; g_s[t] = gamma[t]; b_s[t] = beta[t]; }
    __syncthreads();
    int w = t >> 6, lane = t & 63;
    int mbase = blockIdx.x * 64 + w * 16;
    int mrow = lane & 15, kg = lane >> 4;
    int node = mbase + mrow;
    if (node >= n_nodes) node = n_nodes - 1;

    bf16x8 ah[2], al[2];
#pragma unroll
    for (int s = 0; s < 2; s++) {
        const float* pa = aggr + (size_t)node * 64 + s * 32 + kg * 8;
        float4 v0 = *(const float4*)pa;
        float4 v1 = *(const float4*)(pa + 4);
        float f[8] = {v0.x, v0.y, v0.z, v0.w, v1.x, v1.y, v1.z, v1.w};
#pragma unroll
        for (int j = 0; j < 8; j++) {
            unsigned short hh = f2bf_rne(f[j]);
            ah[s][j] = (short)hh;
            al[s][j] = (short)f2bf_rne(f[j] - bf2f(hh));
        }
    }

    f32x4 acc[8];
#pragma unroll
    for (int tt = 0; tt < 8; tt++) acc[tt] = (f32x4){0.f, 0.f, 0.f, 0.f};
#pragma unroll
    for (int tt = 0; tt < 8; tt++) {
#pragma unroll
        for (int s = 0; s < 2; s++) {
            size_t fi = (size_t)(((tt * 2 + s) * 64 + lane) * 8);
            bf16x8 bh = *(const bf16x8*)(Phf + fi);
            bf16x8 bl = *(const bf16x8*)(Plf + fi);
            acc[tt] = __builtin_amdgcn_mfma_f32_16x16x32_bf16(ah[s], bh, acc[tt], 0, 0, 0);
            acc[tt] = __builtin_amdgcn_mfma_f32_16x16x32_bf16(ah[s], bl, acc[tt], 0, 0, 0);
            acc[tt] = __builtin_amdgcn_mfma_f32_16x16x32_bf16(al[s], bh, acc[tt], 0, 0, 0);
        }
    }

    // D layout: d = tt*16 + (lane&15), node_row = kg*4 + r
#pragma unroll
    for (int r = 0; r < 4; r++) {
        int nr = mbase + kg * 4 + r;
        float vv[8];
        float S = 0.f, Q = 0.f;
#pragma unroll
        for (int tt = 0; tt < 8; tt++) {
            float v = acc[tt][r] + pb_s[tt * 16 + mrow];
            vv[tt] = v;
            S += v;
            Q += v * v;
        }
#pragma unroll
        for (int off = 8; off; off >>= 1) {
            S += __shfl_xor(S, off);
            Q += __shfl_xor(Q, off);
        }
        float mu  = S * (1.f / 128.f);
        float var = Q * (1.f / 128.f) - mu * mu;
        float inv = rsqrtf(var + 1e-5f);
        if (nr < n_nodes) {
#pragma unroll
            for (int tt = 0; tt < 8; tt++) {
                int d = tt * 16 + mrow;
                float o = fmaxf((vv[tt] - mu) * inv * g_s[d] + b_s[d], 0.f);
                out[(size_t)nr * 128 + d] = o;
            }
        }
    }
}

extern "C" void kernel_launch(void* const* d_in, const int* in_sizes, int n_in,
                              void* d_out, int out_size, void* d_ws, size_t ws_size,
                              hipStream_t stream)
{
    const float* x       = (const float*)d_in[0];
    const int*   ei      = (const int*)  d_in[1];
    const float* W       = (const float*)d_in[2];
    const float* att_src = (const float*)d_in[3];
    const float* att_dst = (const float*)d_in[4];
    const float* bias    = (const float*)d_in[5];
    const float* proj_w  = (const float*)d_in[6];
    const float* proj_b  = (const float*)d_in[7];
    const float* gamma   = (const float*)d_in[8];
    const float* beta    = (const float*)d_in[9];

    int N = in_sizes[0] / 128;
    int E = in_sizes[1] / 2;
    const int* srcIdx = ei;
    const int* dstIdx = ei + E;

    char* ws = (char*)d_ws;
    unsigned short* xp = (unsigned short*)ws; ws += (size_t)N * 64 * 2;
    float* aggr    = (float*)ws; ws += (size_t)N * 64 * 4;
    float* a_src   = (float*)ws; ws += (size_t)N * 4 * 4;
    float* a_dst   = (float*)ws; ws += (size_t)N * 4 * 4;
    int*   deg     = (int*)ws;   ws += (size_t)N * 4;
    int*   row_ptr = (int*)ws;   ws += (size_t)(N + 1) * 4;
    int*   partial = (int*)ws;   ws += 256 * 4;
    int*   colsrc  = (int*)ws;   ws += (size_t)E * 4;
    int*   erank   = (int*)ws;   ws += (size_t)E * 4;
    unsigned short* Whf = (unsigned short*)ws; ws += 8192 * 2;
    unsigned short* Wlf = (unsigned short*)ws; ws += 8192 * 2;
    unsigned short* Phf = (unsigned short*)ws; ws += 8192 * 2;
    unsigned short* Plf = (unsigned short*)ws; ws += 8192 * 2;
    float* pb2 = (float*)ws; ws += 128 * 4;

    int nb64 = (N + 63) / 64;
    int nbE  = (E + 255) / 256;
    int nblk = (N + 255) / 256;

    k_prep<<<(16512 + N + 255) / 256, 256, 0, stream>>>(W, bias, proj_w, proj_b,
                                                        Whf, Wlf, Phf, Plf, pb2, deg, N);
    k_xw_mfma<<<nb64, 256, 0, stream>>>(x, Whf, Wlf, att_src, att_dst, xp, a_src, a_dst, N);
    k_rank<<<nbE,  256, 0, stream>>>(dstIdx, deg, erank, E);
    k_scan1<<<nblk, 256, 0, stream>>>(deg, row_ptr, partial, N);
    k_scan2<<<1,    256, 0, stream>>>(partial, nblk);
    k_scan3<<<nblk, 256, 0, stream>>>(deg, row_ptr, partial, N, E);
    k_fill<<<nbE,  256, 0, stream>>>(srcIdx, dstIdx, erank, row_ptr, colsrc, E);
    k_agg2<<<(N + 3) / 4, 256, 0, stream>>>(xp, a_src, a_dst, row_ptr, colsrc, aggr, N);
    k_proj<<<nb64, 256, 0, stream>>>(aggr, Phf, Plf, pb2, gamma, beta, (float*)d_out, N);
}

// Round 6
// 121.202 us; speedup vs baseline: 2.5537x; 1.0023x over previous
//
#include <hip/hip_runtime.h>
#include <hip/hip_bf16.h>

// Fused GATConv + proj + LayerNorm + ReLU. N=50000, E=800000, F_IN=128, H=4, C=16, D=128.
//   k_prep    : zero deg_sh + pack W/proj_w into bf16 hi/lo MFMA fragments; fold bias
//   k_xw_mfma : xp = x@W via split-bf16 MFMA (xp stored bf16) + a_src/a_dst logits (f32)
//   k_rank    : XCD-sharded histogram (deg_sh[blockIdx&7][dst]++), rank captured per edge
//   k_scan1   : per-node 8-shard sum -> per-shard base (in place) + block-exclusive scan
//   k_scan2/3 : block offsets -> global exclusive row_ptr
//   k_fill    : atomic-free scatter: colsrc[row_ptr[d] + shard_base[d] + rank] = src
//   k_agg2    : single-pass segment softmax + aggregation (bf16 gather, high occupancy)
//   k_proj    : (aggr) @ proj_w^T + pb2, LayerNorm, ReLU via split-bf16 MFMA

#define LEAKY(x) ((x) > 0.f ? (x) : 0.2f * (x))
#define NSH 8

typedef __attribute__((ext_vector_type(8))) short bf16x8;
typedef __attribute__((ext_vector_type(4))) float f32x4;

static __device__ __forceinline__ unsigned short f2bf_rne(float f) {
    unsigned u = __float_as_uint(f);
    return (unsigned short)((u + 0x7FFFu + ((u >> 16) & 1u)) >> 16);
}
static __device__ __forceinline__ float bf2f(unsigned short h) {
    return __uint_as_float(((unsigned)h) << 16);
}

// idx [0,8192): W frags; [8192,16384): proj_w frags; [16384,16512): pb2;
// [16512, 16512+8N): deg_sh = 0
__global__ __launch_bounds__(256) void k_prep(
    const float* __restrict__ W, const float* __restrict__ bias,
    const float* __restrict__ proj_w, const float* __restrict__ proj_b,
    unsigned short* __restrict__ Whf, unsigned short* __restrict__ Wlf,
    unsigned short* __restrict__ Phf, unsigned short* __restrict__ Plf,
    float* __restrict__ pb2, int* __restrict__ deg_sh, int n_nodes)
{
    int idx = blockIdx.x * 256 + threadIdx.x;
    if (idx < 8192) {
        int j = idx & 7, lane = (idx >> 3) & 63, ts = idx >> 9;
        int t = ts >> 2, s = ts & 3;
        int k = s * 32 + ((lane >> 4) << 3) + j;
        int n = t * 16 + (lane & 15);
        float w = W[k * 64 + n];
        unsigned short wh = f2bf_rne(w);
        Whf[idx] = wh;
        Wlf[idx] = f2bf_rne(w - bf2f(wh));
    } else if (idx < 16384) {
        int i2 = idx - 8192;
        int j = i2 & 7, lane = (i2 >> 3) & 63, ts = i2 >> 9;
        int t = ts >> 1, s = ts & 1;
        int k = s * 32 + ((lane >> 4) << 3) + j;   // 0..63
        int d = t * 16 + (lane & 15);              // 0..127
        float w = proj_w[d * 64 + k];
        unsigned short wh = f2bf_rne(w);
        Phf[i2] = wh;
        Plf[i2] = f2bf_rne(w - bf2f(wh));
    } else if (idx < 16384 + 128) {
        int d = idx - 16384;
        float s = proj_b[d];
        for (int j = 0; j < 64; j++) s += bias[j] * proj_w[d * 64 + j];
        pb2[d] = s;
    } else if (idx >= 16512 && idx < 16512 + NSH * n_nodes) {
        deg_sh[idx - 16512] = 0;
    }
}

__global__ __launch_bounds__(256) void k_xw_mfma(
    const float* __restrict__ x,
    const unsigned short* __restrict__ Whf, const unsigned short* __restrict__ Wlf,
    const float* __restrict__ att_src, const float* __restrict__ att_dst,
    unsigned short* __restrict__ xp, float* __restrict__ a_src, float* __restrict__ a_dst,
    int n_nodes)
{
    int t = threadIdx.x, w = t >> 6, lane = t & 63;
    int mbase = blockIdx.x * 64 + w * 16;
    int mrow = lane & 15, kg = lane >> 4;
    int node = mbase + mrow;
    if (node >= n_nodes) node = n_nodes - 1;   // clamp; fake rows never stored

    bf16x8 ah[4], al[4];
#pragma unroll
    for (int s = 0; s < 4; s++) {
        const float* px = x + (size_t)node * 128 + s * 32 + kg * 8;
        float4 v0 = *(const float4*)px;
        float4 v1 = *(const float4*)(px + 4);
        float f[8] = {v0.x, v0.y, v0.z, v0.w, v1.x, v1.y, v1.z, v1.w};
#pragma unroll
        for (int j = 0; j < 8; j++) {
            unsigned short h = f2bf_rne(f[j]);
            ah[s][j] = (short)h;
            al[s][j] = (short)f2bf_rne(f[j] - bf2f(h));
        }
    }

    f32x4 acc[4];
#pragma unroll
    for (int tt = 0; tt < 4; tt++) acc[tt] = (f32x4){0.f, 0.f, 0.f, 0.f};

#pragma unroll
    for (int tt = 0; tt < 4; tt++) {
#pragma unroll
        for (int s = 0; s < 4; s++) {
            size_t fi = (size_t)(((tt * 4 + s) * 64 + lane) * 8);
            bf16x8 bh = *(const bf16x8*)(Whf + fi);
            bf16x8 bl = *(const bf16x8*)(Wlf + fi);
            acc[tt] = __builtin_amdgcn_mfma_f32_16x16x32_bf16(ah[s], bh, acc[tt], 0, 0, 0);
            acc[tt] = __builtin_amdgcn_mfma_f32_16x16x32_bf16(ah[s], bl, acc[tt], 0, 0, 0);
            acc[tt] = __builtin_amdgcn_mfma_f32_16x16x32_bf16(al[s], bh, acc[tt], 0, 0, 0);
        }
    }

    // D layout: col=lane&15, row=(lane>>4)*4+reg. Tile tt == head tt.
#pragma unroll
    for (int tt = 0; tt < 4; tt++) {
        float asv = att_src[tt * 16 + mrow];
        float adv = att_dst[tt * 16 + mrow];
#pragma unroll
        for (int r = 0; r < 4; r++) {
            float v = acc[tt][r];
            int n2 = mbase + kg * 4 + r;
            bool ok = (n2 < n_nodes);
            if (ok) xp[(size_t)n2 * 64 + tt * 16 + mrow] = f2bf_rne(v);
            float ts = v * asv;
            float td = v * adv;
#pragma unroll
            for (int off = 8; off; off >>= 1) {
                ts += __shfl_xor(ts, off);
                td += __shfl_xor(td, off);
            }
            if (mrow == 0 && ok) {
                a_src[n2 * 4 + tt] = ts;
                a_dst[n2 * 4 + tt] = td;
            }
        }
    }
}

// XCD-sharded histogram + rank capture. shard = blockIdx&7 tracks the default
// round-robin workgroup->XCD mapping, keeping atomic lines XCD-L2-local.
// Correct for ANY block->shard mapping (shard id is stored with the rank).
__global__ __launch_bounds__(256) void k_rank(const int* __restrict__ dst, int* __restrict__ deg_sh,
                                              int* __restrict__ erank, int E, int n_nodes)
{
    int e = blockIdx.x * 256 + threadIdx.x;
    int shard = blockIdx.x & (NSH - 1);
    if (e < E) {
        int r = atomicAdd(&deg_sh[shard * n_nodes + dst[e]], 1);
        erank[e] = (r << 3) | shard;
    }
}

// Per node g: running-prefix the 8 shard counts in place (deg_sh[s][g] becomes the
// base offset of shard s within node g), total -> block-exclusive scan in row_ptr.
__global__ __launch_bounds__(256) void k_scan1(int* __restrict__ deg_sh, int* __restrict__ row_ptr,
                                               int* __restrict__ partial, int n)
{
    __shared__ int sh[256];
    int t = threadIdx.x, g = blockIdx.x * 256 + t;
    int v = 0;
    if (g < n) {
#pragma unroll
        for (int s = 0; s < NSH; s++) {
            int c = deg_sh[s * n + g];
            deg_sh[s * n + g] = v;
            v += c;
        }
    }
    sh[t] = v; __syncthreads();
    for (int off = 1; off < 256; off <<= 1) {
        int u = (t >= off) ? sh[t - off] : 0;
        __syncthreads();
        sh[t] += u;
        __syncthreads();
    }
    if (g < n) row_ptr[g] = sh[t] - v;          // block-exclusive
    if (t == 255) partial[blockIdx.x] = sh[255]; // block total
}

__global__ __launch_bounds__(256) void k_scan2(int* __restrict__ partial, int nblk)
{
    __shared__ int sh[256];
    int t = threadIdx.x;
    int v = (t < nblk) ? partial[t] : 0;
    sh[t] = v; __syncthreads();
    for (int off = 1; off < 256; off <<= 1) {
        int u = (t >= off) ? sh[t - off] : 0;
        __syncthreads();
        sh[t] += u;
        __syncthreads();
    }
    if (t < nblk) partial[t] = sh[t] - v;
}

__global__ __launch_bounds__(256) void k_scan3(int* __restrict__ row_ptr, const int* __restrict__ partial,
                                               int n, int E_total)
{
    int g = blockIdx.x * 256 + threadIdx.x;
    if (g < n) row_ptr[g] += partial[blockIdx.x];
    if (g == 0) row_ptr[n] = E_total;
}

// Atomic-free CSR fill: slot = row_ptr[d] + shard_base + local rank.
__global__ __launch_bounds__(256) void k_fill(const int* __restrict__ src, const int* __restrict__ dst,
                                              const int* __restrict__ erank, const int* __restrict__ row_ptr,
                                              const int* __restrict__ deg_sh,
                                              int* __restrict__ colsrc, int E, int n_nodes)
{
    int e = blockIdx.x * 256 + threadIdx.x;
    if (e < E) {
        int d = dst[e];
        int er = erank[e];
        int shard = er & (NSH - 1), r = er >> 3;
        colsrc[row_ptr[d] + deg_sh[shard * n_nodes + d] + r] = src[e];
    }
}

// Gather kernel: one node per wave. bf16 xp halves gather bytes; VGPR low for occupancy.
__global__ __launch_bounds__(256, 8) void k_agg2(
    const unsigned short* __restrict__ xp, const float* __restrict__ a_src, const float* __restrict__ a_dst,
    const int* __restrict__ row_ptr, const int* __restrict__ colsrc,
    float* __restrict__ aggr, int n_nodes)
{
    __shared__ int   sstage[4][64];       // 1 KB
    __shared__ float alpha_s[4][64][4];   // 4 KB
    int t = threadIdx.x, w = t >> 6, lane = t & 63, h = lane >> 4;
    int n = blockIdx.x * 4 + w;
    if (n >= n_nodes) return;
    int rp0 = row_ptr[n], rp1 = row_ptr[n + 1];
    float4 ad4 = *(const float4*)&a_dst[(size_t)n * 4];
    float acc = 0.f, den = 0.f;
    for (int base = rp0; base < rp1; base += 64) {
        int cnt = rp1 - base; if (cnt > 64) cnt = 64;
        int s = 0;
        float4 p = make_float4(0.f, 0.f, 0.f, 0.f);
        if (lane < cnt) {
            s = colsrc[base + lane];
            float4 as4 = *(const float4*)&a_src[(size_t)s * 4];
            p.x = __expf(LEAKY(as4.x + ad4.x));
            p.y = __expf(LEAKY(as4.y + ad4.y));
            p.z = __expf(LEAKY(as4.z + ad4.z));
            p.w = __expf(LEAKY(as4.w + ad4.w));
        }
        sstage[w][lane] = s;
        *(float4*)&alpha_s[w][lane][0] = p;
        // same-wave LDS write->read is in-order; no barrier needed
        int cnt4 = (cnt + 3) & ~3;
        for (int j = 0; j < cnt4; j += 4) {
            int s0 = sstage[w][j+0], s1 = sstage[w][j+1];
            int s2 = sstage[w][j+2], s3 = sstage[w][j+3];
            float a0 = alpha_s[w][j+0][h], a1 = alpha_s[w][j+1][h];
            float a2 = alpha_s[w][j+2][h], a3 = alpha_s[w][j+3][h];
            float v0 = bf2f(xp[(size_t)((unsigned)s0 * 64u + lane)]);
            float v1 = bf2f(xp[(size_t)((unsigned)s1 * 64u + lane)]);
            float v2 = bf2f(xp[(size_t)((unsigned)s2 * 64u + lane)]);
            float v3 = bf2f(xp[(size_t)((unsigned)s3 * 64u + lane)]);
            den += a0 + a1 + a2 + a3;
            acc += a0 * v0 + a1 * v1 + a2 * v2 + a3 * v3;
        }
    }
    aggr[(size_t)n * 64 + lane] = acc / (den + 1e-16f);
}

// proj + LN + ReLU via split-bf16 MFMA
__global__ __launch_bounds__(256, 4) void k_proj(
    const float* __restrict__ aggr,
    const unsigned short* __restrict__ Phf, const unsigned short* __restrict__ Plf,
    const float* __restrict__ pb2, const float* __restrict__ gamma, const float* __restrict__ beta,
    float* __restrict__ out, int n_nodes)
{
    __shared__ float pb_s[128], g_s[128], b_s[128];
    int t = threadIdx.x;
    if (t < 128) { pb_s[t] = pb2[t]; g_s[t] = gamma[t]; b_s[t] = beta[t]; }
    __syncthreads();
    int w = t >> 6, lane = t & 63;
    int mbase = blockIdx.x * 64 + w * 16;
    int mrow = lane & 15, kg = lane >> 4;
    int node = mbase + mrow;
    if (node >= n_nodes) node = n_nodes - 1;

    bf16x8 ah[2], al[2];
#pragma unroll
    for (int s = 0; s < 2; s++) {
        const float* pa = aggr + (size_t)node * 64 + s * 32 + kg * 8;
        float4 v0 = *(const float4*)pa;
        float4 v1 = *(const float4*)(pa + 4);
        float f[8] = {v0.x, v0.y, v0.z, v0.w, v1.x, v1.y, v1.z, v1.w};
#pragma unroll
        for (int j = 0; j < 8; j++) {
            unsigned short hh = f2bf_rne(f[j]);
            ah[s][j] = (short)hh;
            al[s][j] = (short)f2bf_rne(f[j] - bf2f(hh));
        }
    }

    f32x4 acc[8];
#pragma unroll
    for (int tt = 0; tt < 8; tt++) acc[tt] = (f32x4){0.f, 0.f, 0.f, 0.f};
#pragma unroll
    for (int tt = 0; tt < 8; tt++) {
#pragma unroll
        for (int s = 0; s < 2; s++) {
            size_t fi = (size_t)(((tt * 2 + s) * 64 + lane) * 8);
            bf16x8 bh = *(const bf16x8*)(Phf + fi);
            bf16x8 bl = *(const bf16x8*)(Plf + fi);
            acc[tt] = __builtin_amdgcn_mfma_f32_16x16x32_bf16(ah[s], bh, acc[tt], 0, 0, 0);
            acc[tt] = __builtin_amdgcn_mfma_f32_16x16x32_bf16(ah[s], bl, acc[tt], 0, 0, 0);
            acc[tt] = __builtin_amdgcn_mfma_f32_16x16x32_bf16(al[s], bh, acc[tt], 0, 0, 0);
        }
    }

    // D layout: d = tt*16 + (lane&15), node_row = kg*4 + r
#pragma unroll
    for (int r = 0; r < 4; r++) {
        int nr = mbase + kg * 4 + r;
        float vv[8];
        float S = 0.f, Q = 0.f;
#pragma unroll
        for (int tt = 0; tt < 8; tt++) {
            float v = acc[tt][r] + pb_s[tt * 16 + mrow];
            vv[tt] = v;
            S += v;
            Q += v * v;
        }
#pragma unroll
        for (int off = 8; off; off >>= 1) {
            S += __shfl_xor(S, off);
            Q += __shfl_xor(Q, off);
        }
        float mu  = S * (1.f / 128.f);
        float var = Q * (1.f / 128.f) - mu * mu;
        float inv = rsqrtf(var + 1e-5f);
        if (nr < n_nodes) {
#pragma unroll
            for (int tt = 0; tt < 8; tt++) {
                int d = tt * 16 + mrow;
                float o = fmaxf((vv[tt] - mu) * inv * g_s[d] + b_s[d], 0.f);
                out[(size_t)nr * 128 + d] = o;
            }
        }
    }
}

extern "C" void kernel_launch(void* const* d_in, const int* in_sizes, int n_in,
                              void* d_out, int out_size, void* d_ws, size_t ws_size,
                              hipStream_t stream)
{
    const float* x       = (const float*)d_in[0];
    const int*   ei      = (const int*)  d_in[1];
    const float* W       = (const float*)d_in[2];
    const float* att_src = (const float*)d_in[3];
    const float* att_dst = (const float*)d_in[4];
    const float* bias    = (const float*)d_in[5];
    const float* proj_w  = (const float*)d_in[6];
    const float* proj_b  = (const float*)d_in[7];
    const float* gamma   = (const float*)d_in[8];
    const float* beta    = (const float*)d_in[9];

    int N = in_sizes[0] / 128;
    int E = in_sizes[1] / 2;
    const int* srcIdx = ei;
    const int* dstIdx = ei + E;

    char* ws = (char*)d_ws;
    unsigned short* xp = (unsigned short*)ws; ws += (size_t)N * 64 * 2;
    float* aggr    = (float*)ws; ws += (size_t)N * 64 * 4;
    float* a_src   = (float*)ws; ws += (size_t)N * 4 * 4;
    float* a_dst   = (float*)ws; ws += (size_t)N * 4 * 4;
    int*   deg_sh  = (int*)ws;   ws += (size_t)NSH * N * 4;
    int*   row_ptr = (int*)ws;   ws += (size_t)(N + 1) * 4;
    int*   partial = (int*)ws;   ws += 256 * 4;
    int*   colsrc  = (int*)ws;   ws += (size_t)E * 4;
    int*   erank   = (int*)ws;   ws += (size_t)E * 4;
    unsigned short* Whf = (unsigned short*)ws; ws += 8192 * 2;
    unsigned short* Wlf = (unsigned short*)ws; ws += 8192 * 2;
    unsigned short* Phf = (unsigned short*)ws; ws += 8192 * 2;
    unsigned short* Plf = (unsigned short*)ws; ws += 8192 * 2;
    float* pb2 = (float*)ws; ws += 128 * 4;

    int nb64 = (N + 63) / 64;
    int nbE  = (E + 255) / 256;
    int nblk = (N + 255) / 256;

    k_prep<<<(16512 + NSH * N + 255) / 256, 256, 0, stream>>>(W, bias, proj_w, proj_b,
                                                              Whf, Wlf, Phf, Plf, pb2, deg_sh, N);
    k_xw_mfma<<<nb64, 256, 0, stream>>>(x, Whf, Wlf, att_src, att_dst, xp, a_src, a_dst, N);
    k_rank<<<nbE,  256, 0, stream>>>(dstIdx, deg_sh, erank, E, N);
    k_scan1<<<nblk, 256, 0, stream>>>(deg_sh, row_ptr, partial, N);
    k_scan2<<<1,    256, 0, stream>>>(partial, nblk);
    k_scan3<<<nblk, 256, 0, stream>>>(row_ptr, partial, N, E);
    k_fill<<<nbE,  256, 0, stream>>>(srcIdx, dstIdx, erank, row_ptr, deg_sh, colsrc, E, N);
    k_agg2<<<(N + 3) / 4, 256, 0, stream>>>(xp, a_src, a_dst, row_ptr, colsrc, aggr, N);
    k_proj<<<nb64, 256, 0, stream>>>(aggr, Phf, Plf, pb2, gamma, beta, (float*)d_out, N);
}

// Round 7
// 110.329 us; speedup vs baseline: 2.8054x; 1.0986x over previous
//
#include <hip/hip_runtime.h>
#include <hip/hip_bf16.h>

// Fused GATConv + proj + LayerNorm + ReLU. N=50000, E=800000, F_IN=128, H=4, C=16, D=128.
//   k_prep    : zero deg + pack W/proj_w into bf16 hi/lo MFMA fragments; fold bias
//   k_xw_rank : FUSED: interleaved blocks do (a) xp = x@W split-bf16 MFMA + logits,
//               (b) deg[dst]++ rank capture. Independent work, overlapped in one dispatch.
//   k_scan1   : block-exclusive scan of deg -> row_ptr, block totals -> partial
//   k_scan23  : each block prefix-scans partials in LDS, adds base -> global row_ptr
//   k_fill    : atomic-free scatter: colsrc[row_ptr[dst]+rank] = src
//   k_agg2    : single-pass segment softmax + aggregation (bf16 gather, bf16 aggr out)
//   k_proj    : aggr(bf16) @ proj_w^T + pb2, LayerNorm, ReLU (32 MFMA, no conversions)

#define LEAKY(x) ((x) > 0.f ? (x) : 0.2f * (x))

typedef __attribute__((ext_vector_type(8))) short bf16x8;
typedef __attribute__((ext_vector_type(4))) float f32x4;

static __device__ __forceinline__ unsigned short f2bf_rne(float f) {
    unsigned u = __float_as_uint(f);
    return (unsigned short)((u + 0x7FFFu + ((u >> 16) & 1u)) >> 16);
}
static __device__ __forceinline__ float bf2f(unsigned short h) {
    return __uint_as_float(((unsigned)h) << 16);
}

// idx [0,8192): W frags; [8192,16384): proj_w frags; [16384,16512): pb2;
// [16512, 16512+N): deg = 0
__global__ __launch_bounds__(256) void k_prep(
    const float* __restrict__ W, const float* __restrict__ bias,
    const float* __restrict__ proj_w, const float* __restrict__ proj_b,
    unsigned short* __restrict__ Whf, unsigned short* __restrict__ Wlf,
    unsigned short* __restrict__ Phf, unsigned short* __restrict__ Plf,
    float* __restrict__ pb2, int* __restrict__ deg, int n_nodes)
{
    int idx = blockIdx.x * 256 + threadIdx.x;
    if (idx < 8192) {
        int j = idx & 7, lane = (idx >> 3) & 63, ts = idx >> 9;
        int t = ts >> 2, s = ts & 3;
        int k = s * 32 + ((lane >> 4) << 3) + j;
        int n = t * 16 + (lane & 15);
        float w = W[k * 64 + n];
        unsigned short wh = f2bf_rne(w);
        Whf[idx] = wh;
        Wlf[idx] = f2bf_rne(w - bf2f(wh));
    } else if (idx < 16384) {
        int i2 = idx - 8192;
        int j = i2 & 7, lane = (i2 >> 3) & 63, ts = i2 >> 9;
        int t = ts >> 1, s = ts & 1;
        int k = s * 32 + ((lane >> 4) << 3) + j;   // 0..63
        int d = t * 16 + (lane & 15);              // 0..127
        float w = proj_w[d * 64 + k];
        unsigned short wh = f2bf_rne(w);
        Phf[i2] = wh;
        Plf[i2] = f2bf_rne(w - bf2f(wh));
    } else if (idx < 16384 + 128) {
        int d = idx - 16384;
        float s = proj_b[d];
        for (int j = 0; j < 64; j++) s += bias[j] * proj_w[d * 64 + j];
        pb2[d] = s;
    } else if (idx >= 16512 && idx < 16512 + n_nodes) {
        deg[idx - 16512] = 0;
    }
}

// FUSED xw + rank. Every P-th block (bid % P == P-1) does one 64-node xw tile
// (xb = bid/P); the rest do one 256-edge rank chunk (rb = bid - bid/P).
// Interleaving makes MFMA compute and atomic latency overlap on the machine.
__global__ __launch_bounds__(256) void k_xw_rank(
    const float* __restrict__ x,
    const unsigned short* __restrict__ Whf, const unsigned short* __restrict__ Wlf,
    const float* __restrict__ att_src, const float* __restrict__ att_dst,
    unsigned short* __restrict__ xp, float* __restrict__ a_src, float* __restrict__ a_dst,
    int n_nodes,
    const int* __restrict__ dst, int* __restrict__ deg, int* __restrict__ erank, int E,
    int P)
{
    int bid = blockIdx.x;
    int t = threadIdx.x;
    if (bid % P != P - 1) {
        // ---- rank path ----
        int rb = bid - bid / P;
        int e = rb * 256 + t;
        if (e < E) erank[e] = atomicAdd(&deg[dst[e]], 1);
        return;
    }
    // ---- xw path ----
    int xb = bid / P;
    int w = t >> 6, lane = t & 63;
    int mbase = xb * 64 + w * 16;
    int mrow = lane & 15, kg = lane >> 4;
    int node = mbase + mrow;
    if (node >= n_nodes) node = n_nodes - 1;   // clamp; fake rows never stored

    bf16x8 ah[4], al[4];
#pragma unroll
    for (int s = 0; s < 4; s++) {
        const float* px = x + (size_t)node * 128 + s * 32 + kg * 8;
        float4 v0 = *(const float4*)px;
        float4 v1 = *(const float4*)(px + 4);
        float f[8] = {v0.x, v0.y, v0.z, v0.w, v1.x, v1.y, v1.z, v1.w};
#pragma unroll
        for (int j = 0; j < 8; j++) {
            unsigned short h = f2bf_rne(f[j]);
            ah[s][j] = (short)h;
            al[s][j] = (short)f2bf_rne(f[j] - bf2f(h));
        }
    }

    f32x4 acc[4];
#pragma unroll
    for (int tt = 0; tt < 4; tt++) acc[tt] = (f32x4){0.f, 0.f, 0.f, 0.f};

#pragma unroll
    for (int tt = 0; tt < 4; tt++) {
#pragma unroll
        for (int s = 0; s < 4; s++) {
            size_t fi = (size_t)(((tt * 4 + s) * 64 + lane) * 8);
            bf16x8 bh = *(const bf16x8*)(Whf + fi);
            bf16x8 bl = *(const bf16x8*)(Wlf + fi);
            acc[tt] = __builtin_amdgcn_mfma_f32_16x16x32_bf16(ah[s], bh, acc[tt], 0, 0, 0);
            acc[tt] = __builtin_amdgcn_mfma_f32_16x16x32_bf16(ah[s], bl, acc[tt], 0, 0, 0);
            acc[tt] = __builtin_amdgcn_mfma_f32_16x16x32_bf16(al[s], bh, acc[tt], 0, 0, 0);
        }
    }

    // D layout: col=lane&15, row=(lane>>4)*4+reg. Tile tt == head tt.
#pragma unroll
    for (int tt = 0; tt < 4; tt++) {
        float asv = att_src[tt * 16 + mrow];
        float adv = att_dst[tt * 16 + mrow];
#pragma unroll
        for (int r = 0; r < 4; r++) {
            float v = acc[tt][r];
            int n2 = mbase + kg * 4 + r;
            bool ok = (n2 < n_nodes);
            if (ok) xp[(size_t)n2 * 64 + tt * 16 + mrow] = f2bf_rne(v);
            float ts = v * asv;
            float td = v * adv;
#pragma unroll
            for (int off = 8; off; off >>= 1) {
                ts += __shfl_xor(ts, off);
                td += __shfl_xor(td, off);
            }
            if (mrow == 0 && ok) {
                a_src[n2 * 4 + tt] = ts;
                a_dst[n2 * 4 + tt] = td;
            }
        }
    }
}

// Block-exclusive scan of deg -> row_ptr; block totals -> partial.
__global__ __launch_bounds__(256) void k_scan1(const int* __restrict__ deg, int* __restrict__ row_ptr,
                                               int* __restrict__ partial, int n)
{
    __shared__ int sh[256];
    int t = threadIdx.x, g = blockIdx.x * 256 + t;
    int v = (g < n) ? deg[g] : 0;
    sh[t] = v; __syncthreads();
    for (int off = 1; off < 256; off <<= 1) {
        int u = (t >= off) ? sh[t - off] : 0;
        __syncthreads();
        sh[t] += u;
        __syncthreads();
    }
    if (g < n) row_ptr[g] = sh[t] - v;          // block-exclusive
    if (t == 255) partial[blockIdx.x] = sh[255]; // block total
}

// Each block prefix-scans all block totals in LDS (nblk <= 256), adds its base.
__global__ __launch_bounds__(256) void k_scan23(int* __restrict__ row_ptr, const int* __restrict__ partial,
                                                int n, int E_total, int nblk)
{
    __shared__ int sh[256];
    int t = threadIdx.x, g = blockIdx.x * 256 + t;
    sh[t] = (t < nblk) ? partial[t] : 0;
    __syncthreads();
    for (int off = 1; off < 256; off <<= 1) {
        int u = (t >= off) ? sh[t - off] : 0;
        __syncthreads();
        sh[t] += u;
        __syncthreads();
    }
    int base = (blockIdx.x > 0) ? sh[blockIdx.x - 1] : 0;  // exclusive prefix of this block
    if (g < n) row_ptr[g] += base;
    if (g == 0) row_ptr[n] = E_total;
}

// Atomic-free CSR fill: slot = row_ptr[dst] + rank.
__global__ __launch_bounds__(256) void k_fill(const int* __restrict__ src, const int* __restrict__ dst,
                                              const int* __restrict__ erank, const int* __restrict__ row_ptr,
                                              int* __restrict__ colsrc, int E)
{
    int e = blockIdx.x * 256 + threadIdx.x;
    if (e < E) {
        colsrc[row_ptr[dst[e]] + erank[e]] = src[e];
    }
}

// Gather kernel: one node per wave. bf16 xp halves gather bytes; bf16 aggr halves write.
__global__ __launch_bounds__(256, 8) void k_agg2(
    const unsigned short* __restrict__ xp, const float* __restrict__ a_src, const float* __restrict__ a_dst,
    const int* __restrict__ row_ptr, const int* __restrict__ colsrc,
    unsigned short* __restrict__ aggr, int n_nodes)
{
    __shared__ int   sstage[4][64];       // 1 KB
    __shared__ float alpha_s[4][64][4];   // 4 KB
    int t = threadIdx.x, w = t >> 6, lane = t & 63, h = lane >> 4;
    int n = blockIdx.x * 4 + w;
    if (n >= n_nodes) return;
    int rp0 = row_ptr[n], rp1 = row_ptr[n + 1];
    float4 ad4 = *(const float4*)&a_dst[(size_t)n * 4];
    float acc = 0.f, den = 0.f;
    for (int base = rp0; base < rp1; base += 64) {
        int cnt = rp1 - base; if (cnt > 64) cnt = 64;
        int s = 0;
        float4 p = make_float4(0.f, 0.f, 0.f, 0.f);
        if (lane < cnt) {
            s = colsrc[base + lane];
            float4 as4 = *(const float4*)&a_src[(size_t)s * 4];
            p.x = __expf(LEAKY(as4.x + ad4.x));
            p.y = __expf(LEAKY(as4.y + ad4.y));
            p.z = __expf(LEAKY(as4.z + ad4.z));
            p.w = __expf(LEAKY(as4.w + ad4.w));
        }
        sstage[w][lane] = s;
        *(float4*)&alpha_s[w][lane][0] = p;
        // same-wave LDS write->read is in-order; no barrier needed
        int cnt4 = (cnt + 3) & ~3;
        for (int j = 0; j < cnt4; j += 4) {
            int s0 = sstage[w][j+0], s1 = sstage[w][j+1];
            int s2 = sstage[w][j+2], s3 = sstage[w][j+3];
            float a0 = alpha_s[w][j+0][h], a1 = alpha_s[w][j+1][h];
            float a2 = alpha_s[w][j+2][h], a3 = alpha_s[w][j+3][h];
            float v0 = bf2f(xp[(size_t)((unsigned)s0 * 64u + lane)]);
            float v1 = bf2f(xp[(size_t)((unsigned)s1 * 64u + lane)]);
            float v2 = bf2f(xp[(size_t)((unsigned)s2 * 64u + lane)]);
            float v3 = bf2f(xp[(size_t)((unsigned)s3 * 64u + lane)]);
            den += a0 + a1 + a2 + a3;
            acc += a0 * v0 + a1 * v1 + a2 * v2 + a3 * v3;
        }
    }
    aggr[(size_t)n * 64 + lane] = f2bf_rne(acc / (den + 1e-16f));
}

// proj + LN + ReLU: aggr is bf16 -> A fragments load directly (lo-term exactly 0),
// weights stay hi/lo split -> 2 MFMA per (tt,s) = 32 total, zero conversion VALU.
__global__ __launch_bounds__(256, 4) void k_proj(
    const unsigned short* __restrict__ aggr,
    const unsigned short* __restrict__ Phf, const unsigned short* __restrict__ Plf,
    const float* __restrict__ pb2, const float* __restrict__ gamma, const float* __restrict__ beta,
    float* __restrict__ out, int n_nodes)
{
    __shared__ float pb_s[128], g_s[128], b_s[128];
    int t = threadIdx.x;
    if (t < 128) { pb_s[t] = pb2[t]; g_s[t] = gamma[t]; b_s[t] = beta[t]; }
    __syncthreads();
    int w = t >> 6, lane = t & 63;
    int mbase = blockIdx.x * 64 + w * 16;
    int mrow = lane & 15, kg = lane >> 4;
    int node = mbase + mrow;
    if (node >= n_nodes) node = n_nodes - 1;

    bf16x8 ah[2];
#pragma unroll
    for (int s = 0; s < 2; s++) {
        ah[s] = *(const bf16x8*)(aggr + (size_t)node * 64 + s * 32 + kg * 8);
    }

    f32x4 acc[8];
#pragma unroll
    for (int tt = 0; tt < 8; tt++) acc[tt] = (f32x4){0.f, 0.f, 0.f, 0.f};
#pragma unroll
    for (int tt = 0; tt < 8; tt++) {
#pragma unroll
        for (int s = 0; s < 2; s++) {
            size_t fi = (size_t)(((tt * 2 + s) * 64 + lane) * 8);
            bf16x8 bh = *(const bf16x8*)(Phf + fi);
            bf16x8 bl = *(const bf16x8*)(Plf + fi);
            acc[tt] = __builtin_amdgcn_mfma_f32_16x16x32_bf16(ah[s], bh, acc[tt], 0, 0, 0);
            acc[tt] = __builtin_amdgcn_mfma_f32_16x16x32_bf16(ah[s], bl, acc[tt], 0, 0, 0);
        }
    }

    // D layout: d = tt*16 + (lane&15), node_row = kg*4 + r
#pragma unroll
    for (int r = 0; r < 4; r++) {
        int nr = mbase + kg * 4 + r;
        float vv[8];
        float S = 0.f, Q = 0.f;
#pragma unroll
        for (int tt = 0; tt < 8; tt++) {
            float v = acc[tt][r] + pb_s[tt * 16 + mrow];
            vv[tt] = v;
            S += v;
            Q += v * v;
        }
#pragma unroll
        for (int off = 8; off; off >>= 1) {
            S += __shfl_xor(S, off);
            Q += __shfl_xor(Q, off);
        }
        float mu  = S * (1.f / 128.f);
        float var = Q * (1.f / 128.f) - mu * mu;
        float inv = rsqrtf(var + 1e-5f);
        if (nr < n_nodes) {
#pragma unroll
            for (int tt = 0; tt < 8; tt++) {
                int d = tt * 16 + mrow;
                float o = fmaxf((vv[tt] - mu) * inv * g_s[d] + b_s[d], 0.f);
                out[(size_t)nr * 128 + d] = o;
            }
        }
    }
}

extern "C" void kernel_launch(void* const* d_in, const int* in_sizes, int n_in,
                              void* d_out, int out_size, void* d_ws, size_t ws_size,
                              hipStream_t stream)
{
    const float* x       = (const float*)d_in[0];
    const int*   ei      = (const int*)  d_in[1];
    const float* W       = (const float*)d_in[2];
    const float* att_src = (const float*)d_in[3];
    const float* att_dst = (const float*)d_in[4];
    const float* bias    = (const float*)d_in[5];
    const float* proj_w  = (const float*)d_in[6];
    const float* proj_b  = (const float*)d_in[7];
    const float* gamma   = (const float*)d_in[8];
    const float* beta    = (const float*)d_in[9];

    int N = in_sizes[0] / 128;
    int E = in_sizes[1] / 2;
    const int* srcIdx = ei;
    const int* dstIdx = ei + E;

    char* ws = (char*)d_ws;
    unsigned short* xp   = (unsigned short*)ws; ws += (size_t)N * 64 * 2;
    unsigned short* aggr = (unsigned short*)ws; ws += (size_t)N * 64 * 2;
    float* a_src   = (float*)ws; ws += (size_t)N * 4 * 4;
    float* a_dst   = (float*)ws; ws += (size_t)N * 4 * 4;
    int*   deg     = (int*)ws;   ws += (size_t)N * 4;
    int*   row_ptr = (int*)ws;   ws += (size_t)(N + 1) * 4;
    int*   partial = (int*)ws;   ws += 256 * 4;
    int*   colsrc  = (int*)ws;   ws += (size_t)E * 4;
    int*   erank   = (int*)ws;   ws += (size_t)E * 4;
    unsigned short* Whf = (unsigned short*)ws; ws += 8192 * 2;
    unsigned short* Wlf = (unsigned short*)ws; ws += 8192 * 2;
    unsigned short* Phf = (unsigned short*)ws; ws += 8192 * 2;
    unsigned short* Plf = (unsigned short*)ws; ws += 8192 * 2;
    float* pb2 = (float*)ws; ws += 128 * 4;

    int nbXw   = (N + 63) / 64;
    int nbRank = (E + 255) / 256;
    int nblk   = (N + 255) / 256;

    // interleave period: one xw block per (P-1) rank blocks
    int P = (nbRank + nbXw - 1) / nbXw + 1;
    int totalFused = nbXw * P;

    k_prep<<<(16512 + N + 255) / 256, 256, 0, stream>>>(W, bias, proj_w, proj_b,
                                                        Whf, Wlf, Phf, Plf, pb2, deg, N);
    k_xw_rank<<<totalFused, 256, 0, stream>>>(x, Whf, Wlf, att_src, att_dst,
                                              xp, a_src, a_dst, N,
                                              dstIdx, deg, erank, E, P);
    k_scan1<<<nblk, 256, 0, stream>>>(deg, row_ptr, partial, N);
    k_scan23<<<nblk, 256, 0, stream>>>(row_ptr, partial, N, E, nblk);
    k_fill<<<nbRank, 256, 0, stream>>>(srcIdx, dstIdx, erank, row_ptr, colsrc, E);
    k_agg2<<<(N + 3) / 4, 256, 0, stream>>>(xp, a_src, a_dst, row_ptr, colsrc, aggr, N);
    k_proj<<<(N + 63) / 64, 256, 0, stream>>>(aggr, Phf, Plf, pb2, gamma, beta, (float*)d_out, N);
}

// Round 8
// 102.000 us; speedup vs baseline: 3.0344x; 1.0817x over previous
//
#include <hip/hip_runtime.h>
#include <hip/hip_bf16.h>

// Fused GATConv + proj + LayerNorm + ReLU. N=50000, E=800000, F_IN=128, H=4, C=16, D=128.
//   k_prep    : zero deg + pack W/proj_w into bf16 hi/lo MFMA fragments; fold bias
//   k_xw_rank : FUSED: interleaved blocks do (a) xp = x@W split-bf16 MFMA + logits,
//               (b) deg[dst]++ rank capture with 4-edge-per-thread ILP (4 independent
//               atomics in flight per lane to cover the return latency).
//   k_scan1   : block-exclusive scan of deg -> row_ptr, block totals -> partial
//   k_scan23  : each block prefix-scans partials in LDS, adds base -> global row_ptr
//   k_fill    : atomic-free scatter: colsrc[row_ptr[dst]+rank] = src
//   k_agg2    : segment softmax + aggregation; wave covers 4 edges per vmem instruction
//               (lane = edge-parity x channel-group, ushort4 loads, shfl_xor reduce)
//   k_proj    : aggr(bf16) @ proj_w^T + pb2, LayerNorm, ReLU (32 MFMA)

#define LEAKY(x) ((x) > 0.f ? (x) : 0.2f * (x))

typedef __attribute__((ext_vector_type(8))) short bf16x8;
typedef __attribute__((ext_vector_type(4))) float f32x4;

static __device__ __forceinline__ unsigned short f2bf_rne(float f) {
    unsigned u = __float_as_uint(f);
    return (unsigned short)((u + 0x7FFFu + ((u >> 16) & 1u)) >> 16);
}
static __device__ __forceinline__ float bf2f(unsigned short h) {
    return __uint_as_float(((unsigned)h) << 16);
}

// idx [0,8192): W frags; [8192,16384): proj_w frags; [16384,16512): pb2;
// [16512, 16512+N): deg = 0
__global__ __launch_bounds__(256) void k_prep(
    const float* __restrict__ W, const float* __restrict__ bias,
    const float* __restrict__ proj_w, const float* __restrict__ proj_b,
    unsigned short* __restrict__ Whf, unsigned short* __restrict__ Wlf,
    unsigned short* __restrict__ Phf, unsigned short* __restrict__ Plf,
    float* __restrict__ pb2, int* __restrict__ deg, int n_nodes)
{
    int idx = blockIdx.x * 256 + threadIdx.x;
    if (idx < 8192) {
        int j = idx & 7, lane = (idx >> 3) & 63, ts = idx >> 9;
        int t = ts >> 2, s = ts & 3;
        int k = s * 32 + ((lane >> 4) << 3) + j;
        int n = t * 16 + (lane & 15);
        float w = W[k * 64 + n];
        unsigned short wh = f2bf_rne(w);
        Whf[idx] = wh;
        Wlf[idx] = f2bf_rne(w - bf2f(wh));
    } else if (idx < 16384) {
        int i2 = idx - 8192;
        int j = i2 & 7, lane = (i2 >> 3) & 63, ts = i2 >> 9;
        int t = ts >> 1, s = ts & 1;
        int k = s * 32 + ((lane >> 4) << 3) + j;   // 0..63
        int d = t * 16 + (lane & 15);              // 0..127
        float w = proj_w[d * 64 + k];
        unsigned short wh = f2bf_rne(w);
        Phf[i2] = wh;
        Plf[i2] = f2bf_rne(w - bf2f(wh));
    } else if (idx < 16384 + 128) {
        int d = idx - 16384;
        float s = proj_b[d];
        for (int j = 0; j < 64; j++) s += bias[j] * proj_w[d * 64 + j];
        pb2[d] = s;
    } else if (idx >= 16512 && idx < 16512 + n_nodes) {
        deg[idx - 16512] = 0;
    }
}

// FUSED xw + rank. Every P-th block (bid % P == P-1) does one 64-node xw tile;
// the rest each rank a 1024-edge chunk (4 edges/thread, independent atomics).
__global__ __launch_bounds__(256) void k_xw_rank(
    const float* __restrict__ x,
    const unsigned short* __restrict__ Whf, const unsigned short* __restrict__ Wlf,
    const float* __restrict__ att_src, const float* __restrict__ att_dst,
    unsigned short* __restrict__ xp, float* __restrict__ a_src, float* __restrict__ a_dst,
    int n_nodes,
    const int* __restrict__ dst, int* __restrict__ deg, int* __restrict__ erank, int E,
    int P)
{
    int bid = blockIdx.x;
    int t = threadIdx.x;
    if (bid % P != P - 1) {
        // ---- rank path: 4 edges per thread, atomics kept independent for ILP ----
        int rb = bid - bid / P;
        int e0 = rb * 1024 + t;
        bool v0 = e0 < E, v1 = e0 + 256 < E, v2 = e0 + 512 < E, v3 = e0 + 768 < E;
        int d0 = 0, d1 = 0, d2 = 0, d3 = 0;
        if (v0) d0 = dst[e0];
        if (v1) d1 = dst[e0 + 256];
        if (v2) d2 = dst[e0 + 512];
        if (v3) d3 = dst[e0 + 768];
        int r0 = 0, r1 = 0, r2 = 0, r3 = 0;
        if (v0) r0 = atomicAdd(&deg[d0], 1);
        if (v1) r1 = atomicAdd(&deg[d1], 1);
        if (v2) r2 = atomicAdd(&deg[d2], 1);
        if (v3) r3 = atomicAdd(&deg[d3], 1);
        if (v0) erank[e0]       = r0;
        if (v1) erank[e0 + 256] = r1;
        if (v2) erank[e0 + 512] = r2;
        if (v3) erank[e0 + 768] = r3;
        return;
    }
    // ---- xw path ----
    int xb = bid / P;
    int w = t >> 6, lane = t & 63;
    int mbase = xb * 64 + w * 16;
    int mrow = lane & 15, kg = lane >> 4;
    int node = mbase + mrow;
    if (node >= n_nodes) node = n_nodes - 1;   // clamp; fake rows never stored

    bf16x8 ah[4], al[4];
#pragma unroll
    for (int s = 0; s < 4; s++) {
        const float* px = x + (size_t)node * 128 + s * 32 + kg * 8;
        float4 v0 = *(const float4*)px;
        float4 v1 = *(const float4*)(px + 4);
        float f[8] = {v0.x, v0.y, v0.z, v0.w, v1.x, v1.y, v1.z, v1.w};
#pragma unroll
        for (int j = 0; j < 8; j++) {
            unsigned short h = f2bf_rne(f[j]);
            ah[s][j] = (short)h;
            al[s][j] = (short)f2bf_rne(f[j] - bf2f(h));
        }
    }

    f32x4 acc[4];
#pragma unroll
    for (int tt = 0; tt < 4; tt++) acc[tt] = (f32x4){0.f, 0.f, 0.f, 0.f};

#pragma unroll
    for (int tt = 0; tt < 4; tt++) {
#pragma unroll
        for (int s = 0; s < 4; s++) {
            size_t fi = (size_t)(((tt * 4 + s) * 64 + lane) * 8);
            bf16x8 bh = *(const bf16x8*)(Whf + fi);
            bf16x8 bl = *(const bf16x8*)(Wlf + fi);
            acc[tt] = __builtin_amdgcn_mfma_f32_16x16x32_bf16(ah[s], bh, acc[tt], 0, 0, 0);
            acc[tt] = __builtin_amdgcn_mfma_f32_16x16x32_bf16(ah[s], bl, acc[tt], 0, 0, 0);
            acc[tt] = __builtin_amdgcn_mfma_f32_16x16x32_bf16(al[s], bh, acc[tt], 0, 0, 0);
        }
    }

    // D layout: col=lane&15, row=(lane>>4)*4+reg. Tile tt == head tt.
#pragma unroll
    for (int tt = 0; tt < 4; tt++) {
        float asv = att_src[tt * 16 + mrow];
        float adv = att_dst[tt * 16 + mrow];
#pragma unroll
        for (int r = 0; r < 4; r++) {
            float v = acc[tt][r];
            int n2 = mbase + kg * 4 + r;
            bool ok = (n2 < n_nodes);
            if (ok) xp[(size_t)n2 * 64 + tt * 16 + mrow] = f2bf_rne(v);
            float ts = v * asv;
            float td = v * adv;
#pragma unroll
            for (int off = 8; off; off >>= 1) {
                ts += __shfl_xor(ts, off);
                td += __shfl_xor(td, off);
            }
            if (mrow == 0 && ok) {
                a_src[n2 * 4 + tt] = ts;
                a_dst[n2 * 4 + tt] = td;
            }
        }
    }
}

// Block-exclusive scan of deg -> row_ptr; block totals -> partial.
__global__ __launch_bounds__(256) void k_scan1(const int* __restrict__ deg, int* __restrict__ row_ptr,
                                               int* __restrict__ partial, int n)
{
    __shared__ int sh[256];
    int t = threadIdx.x, g = blockIdx.x * 256 + t;
    int v = (g < n) ? deg[g] : 0;
    sh[t] = v; __syncthreads();
    for (int off = 1; off < 256; off <<= 1) {
        int u = (t >= off) ? sh[t - off] : 0;
        __syncthreads();
        sh[t] += u;
        __syncthreads();
    }
    if (g < n) row_ptr[g] = sh[t] - v;          // block-exclusive
    if (t == 255) partial[blockIdx.x] = sh[255]; // block total
}

// Each block prefix-scans all block totals in LDS (nblk <= 256), adds its base.
__global__ __launch_bounds__(256) void k_scan23(int* __restrict__ row_ptr, const int* __restrict__ partial,
                                                int n, int E_total, int nblk)
{
    __shared__ int sh[256];
    int t = threadIdx.x, g = blockIdx.x * 256 + t;
    sh[t] = (t < nblk) ? partial[t] : 0;
    __syncthreads();
    for (int off = 1; off < 256; off <<= 1) {
        int u = (t >= off) ? sh[t - off] : 0;
        __syncthreads();
        sh[t] += u;
        __syncthreads();
    }
    int base = (blockIdx.x > 0) ? sh[blockIdx.x - 1] : 0;  // exclusive prefix of this block
    if (g < n) row_ptr[g] += base;
    if (g == 0) row_ptr[n] = E_total;
}

// Atomic-free CSR fill: slot = row_ptr[dst] + rank.
__global__ __launch_bounds__(256) void k_fill(const int* __restrict__ src, const int* __restrict__ dst,
                                              const int* __restrict__ erank, const int* __restrict__ row_ptr,
                                              int* __restrict__ colsrc, int E)
{
    int e = blockIdx.x * 256 + threadIdx.x;
    if (e < E) {
        colsrc[row_ptr[dst[e]] + erank[e]] = src[e];
    }
}

// Gather kernel: one node per wave. Wave covers 4 edges per vmem instruction:
// lane = (edge-parity = lane>>4) x (channel-group = lane&15, 4 bf16 channels each).
__global__ __launch_bounds__(256, 8) void k_agg2(
    const unsigned short* __restrict__ xp, const float* __restrict__ a_src, const float* __restrict__ a_dst,
    const int* __restrict__ row_ptr, const int* __restrict__ colsrc,
    unsigned short* __restrict__ aggr, int n_nodes)
{
    __shared__ int   sstage[4][64];       // 1 KB
    __shared__ float alpha_s[4][64][4];   // 4 KB
    int t = threadIdx.x, w = t >> 6, lane = t & 63;
    int cgrp = lane & 15;     // channels 4*cgrp .. 4*cgrp+3
    int epar = lane >> 4;     // edge parity 0..3
    int h = cgrp >> 2;        // head of my channels
    int n = blockIdx.x * 4 + w;
    if (n >= n_nodes) return;
    int rp0 = row_ptr[n], rp1 = row_ptr[n + 1];
    float4 ad4 = *(const float4*)&a_dst[(size_t)n * 4];
    float ax = 0.f, ay = 0.f, az = 0.f, aw = 0.f, den = 0.f;
    for (int base = rp0; base < rp1; base += 64) {
        int cnt = rp1 - base; if (cnt > 64) cnt = 64;
        int s = 0;
        float4 p = make_float4(0.f, 0.f, 0.f, 0.f);
        if (lane < cnt) {
            s = colsrc[base + lane];
            float4 as4 = *(const float4*)&a_src[(size_t)s * 4];
            p.x = __expf(LEAKY(as4.x + ad4.x));
            p.y = __expf(LEAKY(as4.y + ad4.y));
            p.z = __expf(LEAKY(as4.z + ad4.z));
            p.w = __expf(LEAKY(as4.w + ad4.w));
        }
        sstage[w][lane] = s;
        *(float4*)&alpha_s[w][lane][0] = p;
        // same-wave LDS write->read is in-order; no barrier needed.
        // padded entries (j >= cnt) have alpha 0 / s 0 -> contribute nothing.
        int iters = (cnt + 3) >> 2;
        for (int it = 0; it < iters; ++it) {
            int j = (it << 2) + epar;
            int sj = sstage[w][j];
            float aj = alpha_s[w][j][h];
            ushort4 v = *(const ushort4*)(xp + (size_t)((unsigned)sj * 64u + (cgrp << 2)));
            den += aj;
            ax += aj * bf2f(v.x);
            ay += aj * bf2f(v.y);
            az += aj * bf2f(v.z);
            aw += aj * bf2f(v.w);
        }
    }
    // combine the 4 edge-parity groups (lane^16 flips parity bit0, lane^32 bit1)
    ax += __shfl_xor(ax, 16); ax += __shfl_xor(ax, 32);
    ay += __shfl_xor(ay, 16); ay += __shfl_xor(ay, 32);
    az += __shfl_xor(az, 16); az += __shfl_xor(az, 32);
    aw += __shfl_xor(aw, 16); aw += __shfl_xor(aw, 32);
    den += __shfl_xor(den, 16); den += __shfl_xor(den, 32);
    if (lane < 16) {
        float inv = 1.f / (den + 1e-16f);
        ushort4 o;
        o.x = f2bf_rne(ax * inv);
        o.y = f2bf_rne(ay * inv);
        o.z = f2bf_rne(az * inv);
        o.w = f2bf_rne(aw * inv);
        *(ushort4*)(aggr + (size_t)n * 64 + (cgrp << 2)) = o;
    }
}

// proj + LN + ReLU: aggr is bf16 -> A fragments load directly (lo-term exactly 0),
// weights stay hi/lo split -> 2 MFMA per (tt,s) = 32 total, zero conversion VALU.
__global__ __launch_bounds__(256, 4) void k_proj(
    const unsigned short* __restrict__ aggr,
    const unsigned short* __restrict__ Phf, const unsigned short* __restrict__ Plf,
    const float* __restrict__ pb2, const float* __restrict__ gamma, const float* __restrict__ beta,
    float* __restrict__ out, int n_nodes)
{
    __shared__ float pb_s[128], g_s[128], b_s[128];
    int t = threadIdx.x;
    if (t < 128) { pb_s[t] = pb2[t]; g_s[t] = gamma[t]; b_s[t] = beta[t]; }
    __syncthreads();
    int w = t >> 6, lane = t & 63;
    int mbase = blockIdx.x * 64 + w * 16;
    int mrow = lane & 15, kg = lane >> 4;
    int node = mbase + mrow;
    if (node >= n_nodes) node = n_nodes - 1;

    bf16x8 ah[2];
#pragma unroll
    for (int s = 0; s < 2; s++) {
        ah[s] = *(const bf16x8*)(aggr + (size_t)node * 64 + s * 32 + kg * 8);
    }

    f32x4 acc[8];
#pragma unroll
    for (int tt = 0; tt < 8; tt++) acc[tt] = (f32x4){0.f, 0.f, 0.f, 0.f};
#pragma unroll
    for (int tt = 0; tt < 8; tt++) {
#pragma unroll
        for (int s = 0; s < 2; s++) {
            size_t fi = (size_t)(((tt * 2 + s) * 64 + lane) * 8);
            bf16x8 bh = *(const bf16x8*)(Phf + fi);
            bf16x8 bl = *(const bf16x8*)(Plf + fi);
            acc[tt] = __builtin_amdgcn_mfma_f32_16x16x32_bf16(ah[s], bh, acc[tt], 0, 0, 0);
            acc[tt] = __builtin_amdgcn_mfma_f32_16x16x32_bf16(ah[s], bl, acc[tt], 0, 0, 0);
        }
    }

    // D layout: d = tt*16 + (lane&15), node_row = kg*4 + r
#pragma unroll
    for (int r = 0; r < 4; r++) {
        int nr = mbase + kg * 4 + r;
        float vv[8];
        float S = 0.f, Q = 0.f;
#pragma unroll
        for (int tt = 0; tt < 8; tt++) {
            float v = acc[tt][r] + pb_s[tt * 16 + mrow];
            vv[tt] = v;
            S += v;
            Q += v * v;
        }
#pragma unroll
        for (int off = 8; off; off >>= 1) {
            S += __shfl_xor(S, off);
            Q += __shfl_xor(Q, off);
        }
        float mu  = S * (1.f / 128.f);
        float var = Q * (1.f / 128.f) - mu * mu;
        float inv = rsqrtf(var + 1e-5f);
        if (nr < n_nodes) {
#pragma unroll
            for (int tt = 0; tt < 8; tt++) {
                int d = tt * 16 + mrow;
                float o = fmaxf((vv[tt] - mu) * inv * g_s[d] + b_s[d], 0.f);
                out[(size_t)nr * 128 + d] = o;
            }
        }
    }
}

extern "C" void kernel_launch(void* const* d_in, const int* in_sizes, int n_in,
                              void* d_out, int out_size, void* d_ws, size_t ws_size,
                              hipStream_t stream)
{
    const float* x       = (const float*)d_in[0];
    const int*   ei      = (const int*)  d_in[1];
    const float* W       = (const float*)d_in[2];
    const float* att_src = (const float*)d_in[3];
    const float* att_dst = (const float*)d_in[4];
    const float* bias    = (const float*)d_in[5];
    const float* proj_w  = (const float*)d_in[6];
    const float* proj_b  = (const float*)d_in[7];
    const float* gamma   = (const float*)d_in[8];
    const float* beta    = (const float*)d_in[9];

    int N = in_sizes[0] / 128;
    int E = in_sizes[1] / 2;
    const int* srcIdx = ei;
    const int* dstIdx = ei + E;

    char* ws = (char*)d_ws;
    unsigned short* xp   = (unsigned short*)ws; ws += (size_t)N * 64 * 2;
    unsigned short* aggr = (unsigned short*)ws; ws += (size_t)N * 64 * 2;
    float* a_src   = (float*)ws; ws += (size_t)N * 4 * 4;
    float* a_dst   = (float*)ws; ws += (size_t)N * 4 * 4;
    int*   deg     = (int*)ws;   ws += (size_t)N * 4;
    int*   row_ptr = (int*)ws;   ws += (size_t)(N + 1) * 4;
    int*   partial = (int*)ws;   ws += 256 * 4;
    int*   colsrc  = (int*)ws;   ws += (size_t)E * 4;
    int*   erank   = (int*)ws;   ws += (size_t)E * 4;
    unsigned short* Whf = (unsigned short*)ws; ws += 8192 * 2;
    unsigned short* Wlf = (unsigned short*)ws; ws += 8192 * 2;
    unsigned short* Phf = (unsigned short*)ws; ws += 8192 * 2;
    unsigned short* Plf = (unsigned short*)ws; ws += 8192 * 2;
    float* pb2 = (float*)ws; ws += 128 * 4;

    int nbXw   = (N + 63) / 64;
    int nbRank = (E + 1023) / 1024;
    int nblk   = (N + 255) / 256;

    // interleave period: one xw block per (P-1) rank blocks
    int P = (nbRank + nbXw - 1) / nbXw + 1;
    int totalFused = nbXw * P;

    k_prep<<<(16512 + N + 255) / 256, 256, 0, stream>>>(W, bias, proj_w, proj_b,
                                                        Whf, Wlf, Phf, Plf, pb2, deg, N);
    k_xw_rank<<<totalFused, 256, 0, stream>>>(x, Whf, Wlf, att_src, att_dst,
                                              xp, a_src, a_dst, N,
                                              dstIdx, deg, erank, E, P);
    k_scan1<<<nblk, 256, 0, stream>>>(deg, row_ptr, partial, N);
    k_scan23<<<nblk, 256, 0, stream>>>(row_ptr, partial, N, E, nblk);
    k_fill<<<(E + 255) / 256, 256, 0, stream>>>(srcIdx, dstIdx, erank, row_ptr, colsrc, E);
    k_agg2<<<(N + 3) / 4, 256, 0, stream>>>(xp, a_src, a_dst, row_ptr, colsrc, aggr, N);
    k_proj<<<(N + 63) / 64, 256, 0, stream>>>(aggr, Phf, Plf, pb2, gamma, beta, (float*)d_out, N);
}